// Round 3
// baseline (754.231 us; speedup 1.0000x reference)
//
#include <hip/hip_runtime.h>
#include <hip/hip_bf16.h>
#include <math.h>

// Problem constants (validated against in_sizes at runtime where cheap)
#define FDIM 128
#define NREL 6

// ---------------------------------------------------------------------------
// Tiled f32 GEMM: C[M,128] = A[M,128] @ B[128,128] (+bias), batched over z.
// Block: 256 threads, tile 64(M) x 128(N), K-step 32.
// Thread tile: m = ty*8+i (ty=tid>>5), n = tx*4+j (tx=tid&31) -> float4 LDS reads.
// ---------------------------------------------------------------------------
__launch_bounds__(256)
__global__ void gemm128(const float* __restrict__ A, const float* __restrict__ B,
                        const float* __restrict__ bias, float* __restrict__ C,
                        int M, long long sB, long long sC) {
  B += (long long)blockIdx.z * sB;
  C += (long long)blockIdx.z * sC;
  __shared__ float As[32][64];    // transposed: [k][m]
  __shared__ float Bs[32][128];   // [k][n]
  const int tid = threadIdx.x;
  const int tx = tid & 31;
  const int ty = tid >> 5;
  const int row0 = blockIdx.x * 64;
  float acc[8][4];
#pragma unroll
  for (int i = 0; i < 8; ++i)
#pragma unroll
    for (int j = 0; j < 4; ++j) acc[i][j] = 0.f;

  for (int k0 = 0; k0 < 128; k0 += 32) {
    // stage A (64x32) transposed into As[k][m]
#pragma unroll
    for (int p = 0; p < 2; ++p) {
      int idx = tid + 256 * p;          // 0..511
      int r = idx >> 3, c4 = idx & 7;   // r: row in tile, c4: float4 col
      float4 av = make_float4(0.f, 0.f, 0.f, 0.f);
      if (row0 + r < M)
        av = *(const float4*)(A + (long long)(row0 + r) * FDIM + k0 + c4 * 4);
      As[c4 * 4 + 0][r] = av.x;
      As[c4 * 4 + 1][r] = av.y;
      As[c4 * 4 + 2][r] = av.z;
      As[c4 * 4 + 3][r] = av.w;
    }
    // stage B (32x128)
#pragma unroll
    for (int p = 0; p < 4; ++p) {
      int idx = tid + 256 * p;          // 0..1023
      int r = idx >> 5, c4 = idx & 31;
      *(float4*)&Bs[r][c4 * 4] = *(const float4*)(B + (long long)(k0 + r) * FDIM + c4 * 4);
    }
    __syncthreads();
#pragma unroll
    for (int kk = 0; kk < 32; ++kk) {
      float4 a0 = *(const float4*)&As[kk][ty * 8];
      float4 a1 = *(const float4*)&As[kk][ty * 8 + 4];
      float4 b  = *(const float4*)&Bs[kk][tx * 4];
      float a[8] = {a0.x, a0.y, a0.z, a0.w, a1.x, a1.y, a1.z, a1.w};
      float bb[4] = {b.x, b.y, b.z, b.w};
#pragma unroll
      for (int i = 0; i < 8; ++i)
#pragma unroll
        for (int j = 0; j < 4; ++j) acc[i][j] += a[i] * bb[j];
    }
    __syncthreads();
  }
  float bv[4] = {0.f, 0.f, 0.f, 0.f};
  if (bias) {
    bv[0] = bias[tx * 4 + 0]; bv[1] = bias[tx * 4 + 1];
    bv[2] = bias[tx * 4 + 2]; bv[3] = bias[tx * 4 + 3];
  }
#pragma unroll
  for (int i = 0; i < 8; ++i) {
    int m = row0 + ty * 8 + i;
    if (m < M) {
      float4 o = make_float4(acc[i][0] + bv[0], acc[i][1] + bv[1],
                             acc[i][2] + bv[2], acc[i][3] + bv[3]);
      *(float4*)(C + (long long)m * FDIM + tx * 4) = o;
    }
  }
}

// ---------------------------------------------------------------------------
// CSR construction
// ---------------------------------------------------------------------------
__global__ void hist_kernel(const int* __restrict__ dst, int* __restrict__ deg, int E) {
  int e = blockIdx.x * blockDim.x + threadIdx.x;
  if (e < E) atomicAdd(&deg[dst[e]], 1);
}

__launch_bounds__(1024)
__global__ void scan1(const int* __restrict__ deg, int* __restrict__ incl,
                      int* __restrict__ part, int n) {
  __shared__ int sh[1024];
  int tid = threadIdx.x;
  int i = blockIdx.x * 1024 + tid;
  sh[tid] = (i < n) ? deg[i] : 0;
  __syncthreads();
  for (int o = 1; o < 1024; o <<= 1) {
    int t = (tid >= o) ? sh[tid - o] : 0;
    __syncthreads();
    sh[tid] += t;
    __syncthreads();
  }
  if (i < n) incl[i] = sh[tid];
  if (tid == 1023) part[blockIdx.x] = sh[1023];
}

__global__ void scan2(int* part, int nb) {
  if (threadIdx.x == 0 && blockIdx.x == 0) {
    int run = 0;
    for (int b = 0; b < nb; ++b) { int t = part[b]; part[b] = run; run += t; }
  }
}

__global__ void scan3(const int* __restrict__ incl, const int* __restrict__ part,
                      int* __restrict__ offs, int n) {
  int i = blockIdx.x * blockDim.x + threadIdx.x;
  if (i < n) {
    offs[i + 1] = incl[i] + part[i >> 10];
    if (i == 0) offs[0] = 0;
  }
}

__global__ void scatter_kernel(const int* __restrict__ src, const int* __restrict__ dst,
                               const int* __restrict__ etype, const int* __restrict__ offs,
                               int* __restrict__ cur, int* __restrict__ csrc,
                               int* __restrict__ ctyp, int E) {
  int e = blockIdx.x * blockDim.x + threadIdx.x;
  if (e < E) {
    int d = dst[e];
    int p = offs[d] + atomicAdd(&cur[d], 1);
    csrc[p] = src[e];
    ctyp[p] = etype[e];
  }
}

// ---------------------------------------------------------------------------
// RGCN aggregation: h[n] += sum_e xw[type_e][src_e] / cnt[type_e]
// One block (128 threads) per node; thread = feature.
// ---------------------------------------------------------------------------
__launch_bounds__(128)
__global__ void rgcn_agg(const float* __restrict__ xw, const int* __restrict__ offs,
                         const int* __restrict__ csrc, const int* __restrict__ ctyp,
                         float* __restrict__ h, int N) {
  int node = blockIdx.x;
  int start = offs[node], end = offs[node + 1];
  int tid = threadIdx.x;
  __shared__ int cnt[NREL];
  __shared__ float inv[NREL];
  if (tid < NREL) cnt[tid] = 0;
  __syncthreads();
  for (int e = start + tid; e < end; e += 128) atomicAdd(&cnt[ctyp[e]], 1);
  __syncthreads();
  if (tid < NREL) inv[tid] = cnt[tid] ? 1.f / (float)cnt[tid] : 0.f;
  __syncthreads();
  float acc = 0.f;
  for (int e = start; e < end; ++e) {
    int s = csrc[e];
    int t = ctyp[e];
    acc += xw[((long long)t * N + s) * FDIM + tid] * inv[t];
  }
  h[(long long)node * FDIM + tid] += acc;
}

// ---------------------------------------------------------------------------
// Edge-softmax attention (TransformerConv, heads=1).
// One block (256 thr = 4 waves) per node. Chunked online softmax in LDS.
// out[node] += (sum_e exp(s_e - m) * v[src_e]) / (sum_e exp(s_e - m))
// ---------------------------------------------------------------------------
#define TCH 256
__launch_bounds__(256)
__global__ void attn_kernel(const float* __restrict__ q, const float* __restrict__ k,
                            const float* __restrict__ v, const int* __restrict__ offs,
                            const int* __restrict__ csrc, float* __restrict__ out) {
  int node = blockIdx.x;
  int start = offs[node], end = offs[node + 1];
  int deg = end - start;
  int tid = threadIdx.x;
  int lane = tid & 63;
  int wv = tid >> 6;   // wave id 0..3

  __shared__ float sc[TCH];
  __shared__ float red[256];
  __shared__ float accLds[4][FDIM];
  __shared__ float denLds[4];

  const float qa = q[(long long)node * FDIM + lane];
  const float qb = q[(long long)node * FDIM + 64 + lane];

  float m = -INFINITY, den = 0.f, acc0 = 0.f, acc1 = 0.f;

  for (int c0 = start; c0 < end; c0 += TCH) {
    int cl = min(end - c0, TCH);
    // --- scores: waves split the chunk's edges round-robin ---
    for (int e = c0 + wv; e < c0 + cl; e += 4) {
      int s = csrc[e];
      float p = qa * k[(long long)s * FDIM + lane] + qb * k[(long long)s * FDIM + 64 + lane];
#pragma unroll
      for (int o = 32; o > 0; o >>= 1) p += __shfl_xor(p, o);
      if (lane == 0) sc[e - c0] = p * 0.08838834764831845f;  // 1/sqrt(128)
    }
    __syncthreads();
    // --- chunk max (block reduce) ---
    float lm = -INFINITY;
    for (int i = tid; i < cl; i += 256) lm = fmaxf(lm, sc[i]);
    red[tid] = lm;
    __syncthreads();
    for (int o = 128; o > 0; o >>= 1) {
      if (tid < o) red[tid] = fmaxf(red[tid], red[tid + o]);
      __syncthreads();
    }
    float mnew = fmaxf(m, red[0]);
    float r = expf(m - mnew);   // first chunk: exp(-inf) = 0
    den *= r; acc0 *= r; acc1 *= r;
    m = mnew;
    // --- accumulate exp * v ---
    for (int e = c0 + wv; e < c0 + cl; e += 4) {
      int s = csrc[e];
      float a = expf(sc[e - c0] - m);
      den += a;   // lane-uniform within wave
      acc0 += a * v[(long long)s * FDIM + lane];
      acc1 += a * v[(long long)s * FDIM + 64 + lane];
    }
    __syncthreads();   // protect sc/red before next chunk
  }

  accLds[wv][lane] = acc0;
  accLds[wv][64 + lane] = acc1;
  if (lane == 0) denLds[wv] = den;
  __syncthreads();
  if (tid < FDIM) {
    float s = accLds[0][tid] + accLds[1][tid] + accLds[2][tid] + accLds[3][tid];
    float D = denLds[0] + denLds[1] + denLds[2] + denLds[3];
    float add = (deg > 0) ? s / D : 0.f;
    out[(long long)node * FDIM + tid] += add;
  }
}

// ---------------------------------------------------------------------------
// BatchNorm (training stats) + LeakyReLU
// ---------------------------------------------------------------------------
__launch_bounds__(128)
__global__ void bn_stats(const float* __restrict__ x, float* __restrict__ gsum,
                         float* __restrict__ gsq, int N) {
  int d = threadIdx.x;  // 128 features
  float s = 0.f, qq = 0.f;
  for (int r = blockIdx.x; r < N; r += gridDim.x) {
    float vv = x[(long long)r * FDIM + d];
    s += vv;
    qq += vv * vv;
  }
  atomicAdd(&gsum[d], s);
  atomicAdd(&gsq[d], qq);
}

__global__ void bn_final(const float* __restrict__ gsum, const float* __restrict__ gsq,
                         const float* __restrict__ gamma, const float* __restrict__ beta,
                         float* __restrict__ ss, int N) {
  int d = threadIdx.x;
  if (d < FDIM) {
    float mean = gsum[d] / (float)N;
    float var = gsq[d] / (float)N - mean * mean;
    var = fmaxf(var, 0.f);
    float sc = gamma[d] * rsqrtf(var + 1e-5f);
    ss[d] = sc;
    ss[FDIM + d] = beta[d] - mean * sc;
  }
}

__global__ void bn_apply(float* __restrict__ x, const float* __restrict__ ss, long long total4) {
  long long i = (long long)blockIdx.x * blockDim.x + threadIdx.x;
  if (i < total4) {
    int d0 = (int)((i * 4) & (FDIM - 1));
    float4 vv = ((const float4*)x)[i];
    float y0 = ss[d0 + 0] * vv.x + ss[FDIM + d0 + 0];
    float y1 = ss[d0 + 1] * vv.y + ss[FDIM + d0 + 1];
    float y2 = ss[d0 + 2] * vv.z + ss[FDIM + d0 + 2];
    float y3 = ss[d0 + 3] * vv.w + ss[FDIM + d0 + 3];
    vv.x = (y0 > 0.f) ? y0 : 0.01f * y0;
    vv.y = (y1 > 0.f) ? y1 : 0.01f * y1;
    vv.z = (y2 > 0.f) ? y2 : 0.01f * y2;
    vv.w = (y3 > 0.f) ? y3 : 0.01f * y3;
    ((float4*)x)[i] = vv;
  }
}

// ---------------------------------------------------------------------------
// Launcher
// ---------------------------------------------------------------------------
extern "C" void kernel_launch(void* const* d_in, const int* in_sizes, int n_in,
                              void* d_out, int out_size, void* d_ws, size_t ws_size,
                              hipStream_t stream) {
  const float* x         = (const float*)d_in[0];
  const int*   ei        = (const int*)d_in[1];
  const int*   etype     = (const int*)d_in[2];
  const float* rgcn_w    = (const float*)d_in[3];
  const float* rgcn_root = (const float*)d_in[4];
  const float* rgcn_bias = (const float*)d_in[5];
  const float* wq = (const float*)d_in[6];  const float* bq = (const float*)d_in[7];
  const float* wk = (const float*)d_in[8];  const float* bk = (const float*)d_in[9];
  const float* wv = (const float*)d_in[10]; const float* bv = (const float*)d_in[11];
  const float* wsk = (const float*)d_in[12]; const float* bsk = (const float*)d_in[13];
  const float* gamma = (const float*)d_in[14]; const float* beta = (const float*)d_in[15];

  const int N = in_sizes[0] / FDIM;
  const int E = in_sizes[1] / 2;
  const int* src = ei;
  const int* dst = ei + E;

  // workspace layout (f32 / i32)
  float* ws = (float*)d_ws;
  float* xw = ws;                                  // 6*N*128
  float* qb_ = xw;                                 // reuse after RGCN done
  float* kb_ = xw + (long long)N * FDIM;
  float* vb_ = xw + 2LL * N * FDIM;
  float* h   = ws + 6LL * N * FDIM;                // N*128
  int* ip   = (int*)(h + (long long)N * FDIM);
  int* deg  = ip;                // N
  int* cur  = ip + N;            // N
  int* offs = ip + 2 * N;        // N+1
  int* incl = ip + 3 * N + 1;    // N
  int* part = ip + 4 * N + 1;    // 64
  int* csrc = ip + 4 * N + 65;   // E
  int* ctyp = csrc + E;          // E
  float* gsum = (float*)(ctyp + E);  // 128
  float* gsq  = gsum + FDIM;         // 128
  float* ss   = gsq + FDIM;          // 256

  float* out = (float*)d_out;

  // zero counters
  hipMemsetAsync(deg, 0, (size_t)2 * N * sizeof(int), stream);          // deg + cur
  hipMemsetAsync(gsum, 0, (size_t)2 * FDIM * sizeof(float), stream);    // gsum + gsq

  const int gemmBlocks = (N + 63) / 64;

  // RGCN GEMMs: xw[r] = x @ W_r (batched), h = x @ root + bias
  gemm128<<<dim3(gemmBlocks, 1, NREL), 256, 0, stream>>>(
      x, rgcn_w, nullptr, xw, N, (long long)FDIM * FDIM, (long long)N * FDIM);
  gemm128<<<dim3(gemmBlocks, 1, 1), 256, 0, stream>>>(
      x, rgcn_root, rgcn_bias, h, N, 0, 0);

  // CSR build
  hist_kernel<<<(E + 255) / 256, 256, 0, stream>>>(dst, deg, E);
  int nb = (N + 1023) / 1024;
  scan1<<<nb, 1024, 0, stream>>>(deg, incl, part, N);
  scan2<<<1, 64, 0, stream>>>(part, nb);
  scan3<<<(N + 255) / 256, 256, 0, stream>>>(incl, part, offs, N);
  scatter_kernel<<<(E + 255) / 256, 256, 0, stream>>>(src, dst, etype, offs, cur, csrc, ctyp, E);

  // RGCN aggregate (in-place on h)
  rgcn_agg<<<N, 128, 0, stream>>>(xw, offs, csrc, ctyp, h, N);

  // Transformer projections (q,k,v into reused xw space; skip straight into d_out)
  gemm128<<<dim3(gemmBlocks, 1, 1), 256, 0, stream>>>(h, wq, bq, qb_, N, 0, 0);
  gemm128<<<dim3(gemmBlocks, 1, 1), 256, 0, stream>>>(h, wk, bk, kb_, N, 0, 0);
  gemm128<<<dim3(gemmBlocks, 1, 1), 256, 0, stream>>>(h, wv, bv, vb_, N, 0, 0);
  gemm128<<<dim3(gemmBlocks, 1, 1), 256, 0, stream>>>(h, wsk, bsk, out, N, 0, 0);

  // Edge-softmax attention, accumulates into out
  attn_kernel<<<N, 256, 0, stream>>>(qb_, kb_, vb_, offs, csrc, out);

  // BatchNorm (training stats) + LeakyReLU, in place on out
  bn_stats<<<512, 128, 0, stream>>>(out, gsum, gsq, N);
  bn_final<<<1, 128, 0, stream>>>(gsum, gsq, gamma, beta, ss, N);
  long long total4 = (long long)N * FDIM / 4;
  bn_apply<<<(int)((total4 + 255) / 256), 256, 0, stream>>>(out, ss, total4);
}

// Round 4
// 690.369 us; speedup vs baseline: 1.0925x; 1.0925x over previous
//
#include <hip/hip_runtime.h>
#include <hip/hip_bf16.h>
#include <math.h>

#define FDIM 128
#define NREL 6

// ---------------- bf16 helpers (OCP bf16 = top 16 bits of f32, RNE) --------
static __device__ __forceinline__ unsigned short f2bf(float f) {
  union { float f; unsigned u; } v; v.f = f;
  unsigned r = v.u + 0x7FFFu + ((v.u >> 16) & 1u);
  return (unsigned short)(r >> 16);
}
static __device__ __forceinline__ float bf2f(unsigned us) {
  union { unsigned u; float f; } v; v.u = us << 16; return v.f;
}

// ---------------------------------------------------------------------------
// RGCN fused GEMM: h[M,128] = [x | agg] (M x 896) @ [root; W0..W5] (896 x 128) + bias
// Tile 64(M) x 128(N), 256 threads, K-step 32. agg layout: [N][6*128] node-major.
// ---------------------------------------------------------------------------
__launch_bounds__(256)
__global__ void gemm_rgcn(const float* __restrict__ x, const float* __restrict__ agg,
                          const float* __restrict__ root, const float* __restrict__ w,
                          const float* __restrict__ bias, float* __restrict__ h, int M) {
  __shared__ float As[32][64];
  __shared__ float Bs[32][128];
  const int tid = threadIdx.x;
  const int tx = tid & 31;
  const int ty = tid >> 5;
  const int row0 = blockIdx.x * 64;
  float acc[8][4];
#pragma unroll
  for (int i = 0; i < 8; ++i)
#pragma unroll
    for (int j = 0; j < 4; ++j) acc[i][j] = 0.f;

  for (int k0 = 0; k0 < 896; k0 += 32) {
    const bool fromX = (k0 < 128);
    // stage A (64 x 32), transposed into As[k][m]
#pragma unroll
    for (int p = 0; p < 2; ++p) {
      int idx = tid + 256 * p;
      int r = idx >> 3, c4 = idx & 7;
      int row = row0 + r;
      float4 av = make_float4(0.f, 0.f, 0.f, 0.f);
      if (row < M) {
        const float* ap = fromX ? (x + (long long)row * FDIM + k0)
                                : (agg + (long long)row * (NREL * FDIM) + (k0 - FDIM));
        av = *(const float4*)(ap + c4 * 4);
      }
      As[c4 * 4 + 0][r] = av.x;
      As[c4 * 4 + 1][r] = av.y;
      As[c4 * 4 + 2][r] = av.z;
      As[c4 * 4 + 3][r] = av.w;
    }
    // stage B (32 x 128)
#pragma unroll
    for (int p = 0; p < 4; ++p) {
      int idx = tid + 256 * p;
      int r = idx >> 5, c4 = idx & 31;
      int kr = k0 + r;
      const float* bp = (kr < FDIM) ? (root + (long long)kr * FDIM)
                                    : (w + (long long)(kr - FDIM) * FDIM);
      *(float4*)&Bs[r][c4 * 4] = *(const float4*)(bp + c4 * 4);
    }
    __syncthreads();
#pragma unroll
    for (int kk = 0; kk < 32; ++kk) {
      float4 a0 = *(const float4*)&As[kk][ty * 8];
      float4 a1 = *(const float4*)&As[kk][ty * 8 + 4];
      float4 b  = *(const float4*)&Bs[kk][tx * 4];
      float a[8] = {a0.x, a0.y, a0.z, a0.w, a1.x, a1.y, a1.z, a1.w};
      float bb[4] = {b.x, b.y, b.z, b.w};
#pragma unroll
      for (int i = 0; i < 8; ++i)
#pragma unroll
        for (int j = 0; j < 4; ++j) acc[i][j] += a[i] * bb[j];
    }
    __syncthreads();
  }
  float bv[4];
  bv[0] = bias[tx * 4 + 0]; bv[1] = bias[tx * 4 + 1];
  bv[2] = bias[tx * 4 + 2]; bv[3] = bias[tx * 4 + 3];
#pragma unroll
  for (int i = 0; i < 8; ++i) {
    int m = row0 + ty * 8 + i;
    if (m < M) {
      float4 o = make_float4(acc[i][0] + bv[0], acc[i][1] + bv[1],
                             acc[i][2] + bv[2], acc[i][3] + bv[3]);
      *(float4*)(h + (long long)m * FDIM + tx * 4) = o;
    }
  }
}

// ---------------------------------------------------------------------------
// q,k,v,skip projections in one z=4 launch. z=0 -> q (f32), z=1 -> k (bf16),
// z=2 -> v (bf16), z=3 -> skip (f32, straight into d_out).
// ---------------------------------------------------------------------------
struct TPack {
  const float* W[4];
  const float* bias[4];
  float* Cq;
  unsigned short* Ck;
  unsigned short* Cv;
  float* Cs;
};

__launch_bounds__(256)
__global__ void gemm_qkvs(const float* __restrict__ A, TPack P, int M) {
  const int z = blockIdx.z;
  const float* __restrict__ B = P.W[z];
  const float* __restrict__ bias = P.bias[z];
  __shared__ float As[32][64];
  __shared__ float Bs[32][128];
  const int tid = threadIdx.x;
  const int tx = tid & 31;
  const int ty = tid >> 5;
  const int row0 = blockIdx.x * 64;
  float acc[8][4];
#pragma unroll
  for (int i = 0; i < 8; ++i)
#pragma unroll
    for (int j = 0; j < 4; ++j) acc[i][j] = 0.f;

  for (int k0 = 0; k0 < 128; k0 += 32) {
#pragma unroll
    for (int p = 0; p < 2; ++p) {
      int idx = tid + 256 * p;
      int r = idx >> 3, c4 = idx & 7;
      float4 av = make_float4(0.f, 0.f, 0.f, 0.f);
      if (row0 + r < M)
        av = *(const float4*)(A + (long long)(row0 + r) * FDIM + k0 + c4 * 4);
      As[c4 * 4 + 0][r] = av.x;
      As[c4 * 4 + 1][r] = av.y;
      As[c4 * 4 + 2][r] = av.z;
      As[c4 * 4 + 3][r] = av.w;
    }
#pragma unroll
    for (int p = 0; p < 4; ++p) {
      int idx = tid + 256 * p;
      int r = idx >> 5, c4 = idx & 31;
      *(float4*)&Bs[r][c4 * 4] = *(const float4*)(B + (long long)(k0 + r) * FDIM + c4 * 4);
    }
    __syncthreads();
#pragma unroll
    for (int kk = 0; kk < 32; ++kk) {
      float4 a0 = *(const float4*)&As[kk][ty * 8];
      float4 a1 = *(const float4*)&As[kk][ty * 8 + 4];
      float4 b  = *(const float4*)&Bs[kk][tx * 4];
      float a[8] = {a0.x, a0.y, a0.z, a0.w, a1.x, a1.y, a1.z, a1.w};
      float bb[4] = {b.x, b.y, b.z, b.w};
#pragma unroll
      for (int i = 0; i < 8; ++i)
#pragma unroll
        for (int j = 0; j < 4; ++j) acc[i][j] += a[i] * bb[j];
    }
    __syncthreads();
  }
  float bv[4];
  bv[0] = bias[tx * 4 + 0]; bv[1] = bias[tx * 4 + 1];
  bv[2] = bias[tx * 4 + 2]; bv[3] = bias[tx * 4 + 3];

  if (z == 1 || z == 2) {
    unsigned short* C = (z == 1) ? P.Ck : P.Cv;
#pragma unroll
    for (int i = 0; i < 8; ++i) {
      int m = row0 + ty * 8 + i;
      if (m < M) {
        unsigned short h0 = f2bf(acc[i][0] + bv[0]);
        unsigned short h1 = f2bf(acc[i][1] + bv[1]);
        unsigned short h2 = f2bf(acc[i][2] + bv[2]);
        unsigned short h3 = f2bf(acc[i][3] + bv[3]);
        uint2 uu;
        uu.x = (unsigned)h0 | ((unsigned)h1 << 16);
        uu.y = (unsigned)h2 | ((unsigned)h3 << 16);
        *(uint2*)(C + (long long)m * FDIM + tx * 4) = uu;
      }
    }
  } else {
    float* C = (z == 0) ? P.Cq : P.Cs;
#pragma unroll
    for (int i = 0; i < 8; ++i) {
      int m = row0 + ty * 8 + i;
      if (m < M) {
        float4 o = make_float4(acc[i][0] + bv[0], acc[i][1] + bv[1],
                               acc[i][2] + bv[2], acc[i][3] + bv[3]);
        *(float4*)(C + (long long)m * FDIM + tx * 4) = o;
      }
    }
  }
}

// ---------------------------------------------------------------------------
// CSR construction
// ---------------------------------------------------------------------------
__global__ void hist_kernel(const int* __restrict__ dst, int* __restrict__ deg, int E) {
  int e = blockIdx.x * blockDim.x + threadIdx.x;
  if (e < E) atomicAdd(&deg[dst[e]], 1);
}

__launch_bounds__(1024)
__global__ void scan1(const int* __restrict__ deg, int* __restrict__ incl,
                      int* __restrict__ part, int n) {
  __shared__ int sh[1024];
  int tid = threadIdx.x;
  int i = blockIdx.x * 1024 + tid;
  sh[tid] = (i < n) ? deg[i] : 0;
  __syncthreads();
  for (int o = 1; o < 1024; o <<= 1) {
    int t = (tid >= o) ? sh[tid - o] : 0;
    __syncthreads();
    sh[tid] += t;
    __syncthreads();
  }
  if (i < n) incl[i] = sh[tid];
  if (tid == 1023) part[blockIdx.x] = sh[1023];
}

__global__ void scan2(int* part, int nb) {
  if (threadIdx.x == 0 && blockIdx.x == 0) {
    int run = 0;
    for (int b = 0; b < nb; ++b) { int t = part[b]; part[b] = run; run += t; }
  }
}

__global__ void scan3(const int* __restrict__ incl, const int* __restrict__ part,
                      int* __restrict__ offs, int n) {
  int i = blockIdx.x * blockDim.x + threadIdx.x;
  if (i < n) {
    offs[i + 1] = incl[i] + part[i >> 10];
    if (i == 0) offs[0] = 0;
  }
}

__global__ void scatter_kernel(const int* __restrict__ src, const int* __restrict__ dst,
                               const int* __restrict__ etype, const int* __restrict__ offs,
                               int* __restrict__ cur, int* __restrict__ csrc,
                               int* __restrict__ ctyp, int E) {
  int e = blockIdx.x * blockDim.x + threadIdx.x;
  if (e < E) {
    int d = dst[e];
    int p = offs[d] + atomicAdd(&cur[d], 1);
    csrc[p] = src[e];
    ctyp[p] = etype[e];
  }
}

// ---------------------------------------------------------------------------
// RGCN aggregation (aggregate-first): agg[n][r][:] = mean over r-edges of x[src].
// One WAVE per node (4 nodes / 256-thr block). Lane owns features (2l, 2l+1).
// No LDS, no syncs; 1-deep prefetch of next x row.
// ---------------------------------------------------------------------------
__launch_bounds__(256)
__global__ void rgcn_agg(const float* __restrict__ x, const int* __restrict__ offs,
                         const int* __restrict__ csrc, const int* __restrict__ ctyp,
                         float* __restrict__ agg, int N) {
  int node = blockIdx.x * 4 + (threadIdx.x >> 6);
  if (node >= N) return;
  int lane = threadIdx.x & 63;
  int start = offs[node], end = offs[node + 1];

  float a0x = 0.f, a0y = 0.f, a1x = 0.f, a1y = 0.f, a2x = 0.f, a2y = 0.f;
  float a3x = 0.f, a3y = 0.f, a4x = 0.f, a4y = 0.f, a5x = 0.f, a5y = 0.f;
  int c0 = 0, c1 = 0, c2 = 0, c3 = 0, c4 = 0, c5 = 0;

  float2 xv = make_float2(0.f, 0.f);
  if (start < end) {
    int s = csrc[start];
    xv = ((const float2*)(x + (long long)s * FDIM))[lane];
  }
  for (int e = start; e < end; ++e) {
    float2 cv = xv;
    int r = ctyp[e];
    if (e + 1 < end) {
      int s2 = csrc[e + 1];
      xv = ((const float2*)(x + (long long)s2 * FDIM))[lane];
    }
    switch (r) {
      case 0: a0x += cv.x; a0y += cv.y; ++c0; break;
      case 1: a1x += cv.x; a1y += cv.y; ++c1; break;
      case 2: a2x += cv.x; a2y += cv.y; ++c2; break;
      case 3: a3x += cv.x; a3y += cv.y; ++c3; break;
      case 4: a4x += cv.x; a4y += cv.y; ++c4; break;
      default: a5x += cv.x; a5y += cv.y; ++c5; break;
    }
  }
  float i0 = c0 ? 1.f / (float)c0 : 0.f;
  float i1 = c1 ? 1.f / (float)c1 : 0.f;
  float i2 = c2 ? 1.f / (float)c2 : 0.f;
  float i3 = c3 ? 1.f / (float)c3 : 0.f;
  float i4 = c4 ? 1.f / (float)c4 : 0.f;
  float i5 = c5 ? 1.f / (float)c5 : 0.f;
  float2* ap = (float2*)(agg + (long long)node * (NREL * FDIM));
  ap[0 * 64 + lane] = make_float2(a0x * i0, a0y * i0);
  ap[1 * 64 + lane] = make_float2(a1x * i1, a1y * i1);
  ap[2 * 64 + lane] = make_float2(a2x * i2, a2y * i2);
  ap[3 * 64 + lane] = make_float2(a3x * i3, a3y * i3);
  ap[4 * 64 + lane] = make_float2(a4x * i4, a4y * i4);
  ap[5 * 64 + lane] = make_float2(a5x * i5, a5y * i5);
}

// ---------------------------------------------------------------------------
// TransformerConv edge-softmax, single-pass online softmax, one WAVE per node.
// k,v stored as bf16 (packed 2/lane); q f32. Butterfly shuffle -> all lanes
// hold the score; den/acc rescaled online. 1-deep prefetch of next k/v rows.
// ---------------------------------------------------------------------------
__launch_bounds__(256)
__global__ void attn_kernel(const float* __restrict__ q,
                            const unsigned short* __restrict__ kb,
                            const unsigned short* __restrict__ vb,
                            const int* __restrict__ offs, const int* __restrict__ csrc,
                            float* __restrict__ out, int N) {
  int node = blockIdx.x * 4 + (threadIdx.x >> 6);
  if (node >= N) return;
  int lane = threadIdx.x & 63;
  int start = offs[node], end = offs[node + 1];
  if (start >= end) return;  // no incoming edges: attention adds 0

  float2 qf = ((const float2*)(q + (long long)node * FDIM))[lane];
  float m = -INFINITY, den = 0.f, acc0 = 0.f, acc1 = 0.f;

  int s = csrc[start];
  unsigned kk = ((const unsigned*)(kb + (long long)s * FDIM))[lane];
  unsigned vv = ((const unsigned*)(vb + (long long)s * FDIM))[lane];

  for (int e = start; e < end; ++e) {
    unsigned ck = kk, cv = vv;
    if (e + 1 < end) {
      int s2 = csrc[e + 1];
      kk = ((const unsigned*)(kb + (long long)s2 * FDIM))[lane];
      vv = ((const unsigned*)(vb + (long long)s2 * FDIM))[lane];
    }
    float p = qf.x * bf2f(ck & 0xFFFFu) + qf.y * bf2f(ck >> 16);
#pragma unroll
    for (int o = 32; o; o >>= 1) p += __shfl_xor(p, o);
    float sc = p * 0.08838834764831845f;  // 1/sqrt(128)
    float mn = fmaxf(m, sc);
    float scale = __expf(m - mn);  // first edge: exp(-inf) = 0
    float a = __expf(sc - mn);
    den = den * scale + a;
    acc0 = acc0 * scale + a * bf2f(cv & 0xFFFFu);
    acc1 = acc1 * scale + a * bf2f(cv >> 16);
    m = mn;
  }
  float inv = 1.f / den;
  float2* op = (float2*)(out + (long long)node * FDIM);
  float2 o = op[lane];
  o.x += acc0 * inv;
  o.y += acc1 * inv;
  op[lane] = o;
}

// ---------------------------------------------------------------------------
// BatchNorm (training stats) + LeakyReLU
// ---------------------------------------------------------------------------
__launch_bounds__(128)
__global__ void bn_stats(const float* __restrict__ x, float* __restrict__ gsum,
                         float* __restrict__ gsq, int N) {
  int d = threadIdx.x;
  float s = 0.f, qq = 0.f;
  for (int r = blockIdx.x; r < N; r += gridDim.x) {
    float vv = x[(long long)r * FDIM + d];
    s += vv;
    qq += vv * vv;
  }
  atomicAdd(&gsum[d], s);
  atomicAdd(&gsq[d], qq);
}

__global__ void bn_final(const float* __restrict__ gsum, const float* __restrict__ gsq,
                         const float* __restrict__ gamma, const float* __restrict__ beta,
                         float* __restrict__ ss, int N) {
  int d = threadIdx.x;
  if (d < FDIM) {
    float mean = gsum[d] / (float)N;
    float var = gsq[d] / (float)N - mean * mean;
    var = fmaxf(var, 0.f);
    float sc = gamma[d] * rsqrtf(var + 1e-5f);
    ss[d] = sc;
    ss[FDIM + d] = beta[d] - mean * sc;
  }
}

__global__ void bn_apply(float* __restrict__ x, const float* __restrict__ ss, long long total4) {
  long long i = (long long)blockIdx.x * blockDim.x + threadIdx.x;
  if (i < total4) {
    int d0 = (int)((i * 4) & (FDIM - 1));
    float4 vv = ((const float4*)x)[i];
    float y0 = ss[d0 + 0] * vv.x + ss[FDIM + d0 + 0];
    float y1 = ss[d0 + 1] * vv.y + ss[FDIM + d0 + 1];
    float y2 = ss[d0 + 2] * vv.z + ss[FDIM + d0 + 2];
    float y3 = ss[d0 + 3] * vv.w + ss[FDIM + d0 + 3];
    vv.x = (y0 > 0.f) ? y0 : 0.01f * y0;
    vv.y = (y1 > 0.f) ? y1 : 0.01f * y1;
    vv.z = (y2 > 0.f) ? y2 : 0.01f * y2;
    vv.w = (y3 > 0.f) ? y3 : 0.01f * y3;
    ((float4*)x)[i] = vv;
  }
}

// ---------------------------------------------------------------------------
// Launcher
// ---------------------------------------------------------------------------
extern "C" void kernel_launch(void* const* d_in, const int* in_sizes, int n_in,
                              void* d_out, int out_size, void* d_ws, size_t ws_size,
                              hipStream_t stream) {
  const float* x         = (const float*)d_in[0];
  const int*   ei        = (const int*)d_in[1];
  const int*   etype     = (const int*)d_in[2];
  const float* rgcn_w    = (const float*)d_in[3];
  const float* rgcn_root = (const float*)d_in[4];
  const float* rgcn_bias = (const float*)d_in[5];
  const float* wq = (const float*)d_in[6];  const float* bq = (const float*)d_in[7];
  const float* wk = (const float*)d_in[8];  const float* bk = (const float*)d_in[9];
  const float* wv = (const float*)d_in[10]; const float* bv = (const float*)d_in[11];
  const float* wsk = (const float*)d_in[12]; const float* bsk = (const float*)d_in[13];
  const float* gamma = (const float*)d_in[14]; const float* beta = (const float*)d_in[15];

  const int N = in_sizes[0] / FDIM;
  const int E = in_sizes[1] / 2;
  const int* src = ei;
  const int* dst = ei + E;

  // ---- workspace layout ----
  // agg region (N*768 f32 = 153.6MB) is reused after the RGCN GEMM for q/k/v.
  float* ws  = (float*)d_ws;
  float* agg = ws;                                   // N * 768 f32
  float* qb  = agg;                                  // N * 128 f32   (reuse)
  unsigned short* kbuf = (unsigned short*)(agg + (long long)N * FDIM);  // N*128 bf16
  unsigned short* vbuf = kbuf + (long long)N * FDIM;                    // N*128 bf16
  float* h   = ws + (long long)N * (NREL * FDIM);    // N * 128 f32
  int* ip   = (int*)(h + (long long)N * FDIM);
  int* deg  = ip;                 // N
  int* cur  = ip + N;             // N
  int* offs = ip + 2 * N;         // N+1
  int* incl = ip + 3 * N + 1;     // N
  int* part = ip + 4 * N + 1;     // 64
  int* csrc = ip + 4 * N + 65;    // E
  int* ctyp = csrc + E;           // E
  float* gsum = (float*)(ctyp + E);   // 128
  float* gsq  = gsum + FDIM;          // 128
  float* ss   = gsq + FDIM;           // 256

  float* out = (float*)d_out;

  hipMemsetAsync(deg, 0, (size_t)2 * N * sizeof(int), stream);        // deg + cur
  hipMemsetAsync(gsum, 0, (size_t)2 * FDIM * sizeof(float), stream);  // gsum + gsq

  // ---- CSR build (by dst) ----
  hist_kernel<<<(E + 255) / 256, 256, 0, stream>>>(dst, deg, E);
  int nb = (N + 1023) / 1024;
  scan1<<<nb, 1024, 0, stream>>>(deg, incl, part, N);
  scan2<<<1, 64, 0, stream>>>(part, nb);
  scan3<<<(N + 255) / 256, 256, 0, stream>>>(incl, part, offs, N);
  scatter_kernel<<<(E + 255) / 256, 256, 0, stream>>>(src, dst, etype, offs, cur, csrc, ctyp, E);

  const int nodeBlocks = (N + 3) / 4;
  const int gemmBlocks = (N + 63) / 64;

  // ---- RGCN: aggregate-first, then one K=896 GEMM ----
  rgcn_agg<<<nodeBlocks, 256, 0, stream>>>(x, offs, csrc, ctyp, agg, N);
  gemm_rgcn<<<gemmBlocks, 256, 0, stream>>>(x, agg, rgcn_root, rgcn_w, rgcn_bias, h, N);

  // ---- q,k,v,skip projections (k,v emitted as bf16; skip straight into out) ----
  TPack P;
  P.W[0] = wq;  P.W[1] = wk;  P.W[2] = wv;  P.W[3] = wsk;
  P.bias[0] = bq; P.bias[1] = bk; P.bias[2] = bv; P.bias[3] = bsk;
  P.Cq = qb; P.Ck = kbuf; P.Cv = vbuf; P.Cs = out;
  gemm_qkvs<<<dim3(gemmBlocks, 1, 4), 256, 0, stream>>>(h, P, N);

  // ---- edge-softmax attention (accumulates into out) ----
  attn_kernel<<<nodeBlocks, 256, 0, stream>>>(qb, kbuf, vbuf, offs, csrc, out, N);

  // ---- BatchNorm (training stats) + LeakyReLU, in place on out ----
  bn_stats<<<512, 128, 0, stream>>>(out, gsum, gsq, N);
  bn_final<<<1, 128, 0, stream>>>(gsum, gsq, gamma, beta, ss, N);
  long long total4 = (long long)N * FDIM / 4;
  bn_apply<<<(int)((total4 + 255) / 256), 256, 0, stream>>>(out, ss, total4);
}

// Round 5
// 449.792 us; speedup vs baseline: 1.6768x; 1.5349x over previous
//
#include <hip/hip_runtime.h>
#include <hip/hip_bf16.h>
#include <math.h>

#define FDIM 128
#define NREL 6

typedef _Float16 half8 __attribute__((ext_vector_type(8)));
typedef float f32x4 __attribute__((ext_vector_type(4)));

// ---------------- bf16 helpers (OCP bf16 = top 16 bits of f32, RNE) --------
static __device__ __forceinline__ unsigned short f2bf(float f) {
  union { float f; unsigned u; } v; v.f = f;
  unsigned r = v.u + 0x7FFFu + ((v.u >> 16) & 1u);
  return (unsigned short)(r >> 16);
}
static __device__ __forceinline__ float bf2f(unsigned us) {
  union { unsigned u; float f; } v; v.u = us << 16; return v.f;
}
// ---------------- fp16 helpers ----------------------------------------------
static __device__ __forceinline__ unsigned short f2h(float f) {
  union { _Float16 h; unsigned short u; } p; p.h = (_Float16)f; return p.u;
}
static __device__ __forceinline__ float h2f(unsigned short u) {
  union { unsigned short u; _Float16 h; } p; p.u = u; return (float)p.h;
}

// ---------------------------------------------------------------------------
// dtype conversion passes
// ---------------------------------------------------------------------------
__global__ void cvt_x_kernel(const float* __restrict__ x, unsigned short* __restrict__ xh,
                             int n4) {
  int i = blockIdx.x * 256 + threadIdx.x;
  if (i < n4) {
    float4 v = ((const float4*)x)[i];
    union { _Float16 h[4]; uint2 u; } p;
    p.h[0] = (_Float16)v.x; p.h[1] = (_Float16)v.y;
    p.h[2] = (_Float16)v.z; p.h[3] = (_Float16)v.w;
    ((uint2*)xh)[i] = p.u;
  }
}

// Bt_rgcn[n][kk] (n<128, kk<896) = (kk<128 ? root[kk][n] : w[kk-128][n]) as fp16
__global__ void cvt_wr_kernel(const float* __restrict__ root, const float* __restrict__ w,
                              unsigned short* __restrict__ bt) {
  int i = blockIdx.x * 256 + threadIdx.x;
  if (i < 896 * 128) {
    int n = i / 896, kk = i - n * 896;
    float v = (kk < 128) ? root[kk * 128 + n] : w[(long long)(kk - 128) * 128 + n];
    bt[i] = f2h(v);
  }
}

// Bt_qkvs[z][n][kk] = W_z[kk][n] as fp16
struct WPtrs { const float* W[4]; };
__global__ void cvt_wq_kernel(WPtrs wp, unsigned short* __restrict__ bt) {
  int i = blockIdx.x * 256 + threadIdx.x;
  if (i < 4 * 128 * 128) {
    int z = i >> 14;
    int r = i & 16383;
    int n = r >> 7, kk = r & 127;
    bt[i] = f2h(wp.W[z][kk * 128 + n]);
  }
}

// ---------------------------------------------------------------------------
// fp16 MFMA GEMM, tile 64(M) x 128(N), BK=64, 256 thr = 4 waves (2M x 2N).
// A [M][K] fp16 (MODE0: K=896 split x_h|agg_h; MODE1: K=128 h_h, z=4 weights).
// B passed pre-transposed [z][128(n)][K] fp16. XOR-swizzled LDS (T2) so the
// stride-128B ds_read_b128 fragment reads are conflict-free.
// MFMA frag maps (verified, cdna4 docs): A row=lane&15, k=(lane>>4)*8+i;
// B col=lane&15, same k; C/D col=lane&15, row=(lane>>4)*4+reg.
// ---------------------------------------------------------------------------
struct GArgs {
  const unsigned short* Ax;    // fp16 [M][128]  (x_h or h_h)
  const unsigned short* Aagg;  // fp16 [M][768]  (MODE0)
  const unsigned short* Bt;    // fp16 [z][128][K]
  const float* bias[4];
  float* q; unsigned short* kb; unsigned short* vb; float* sk;  // MODE1 outputs
  unsigned short* h;                                            // MODE0 output
  int M, K;
};

template <int MODE>
__launch_bounds__(256)
__global__ void gemm_mfma(GArgs g) {
  __shared__ unsigned short Ah[64 * 64];    // [r][8 x 16B units], swizzled
  __shared__ unsigned short Bh[128 * 64];   // [n][8 x 16B units], swizzled
  const int tid = threadIdx.x;
  const int lane = tid & 63;
  const int wid = tid >> 6;
  const int wm = wid >> 1, wn = wid & 1;
  const int lr = lane & 15, lk = lane >> 4;
  const int m0 = blockIdx.x * 64;
  const int z = (MODE == 1) ? blockIdx.z : 0;
  const unsigned short* Bt = g.Bt + (long long)z * 128 * g.K;
  const int K = g.K;
  const int M = g.M;

  f32x4 acc[2][4];
#pragma unroll
  for (int a = 0; a < 2; ++a)
#pragma unroll
    for (int b = 0; b < 4; ++b) { acc[a][b][0] = 0.f; acc[a][b][1] = 0.f; acc[a][b][2] = 0.f; acc[a][b][3] = 0.f; }

  for (int k0 = 0; k0 < K; k0 += 64) {
    __syncthreads();
    // ---- stage A: 64 rows x 8 col16 units ----
#pragma unroll
    for (int p = 0; p < 2; ++p) {
      int idx = tid + 256 * p;
      int r = idx >> 3, c = idx & 7;
      int row = m0 + r; if (row > M - 1) row = M - 1;   // clamp tail (store guarded)
      const unsigned short* srcp;
      if (MODE == 0)
        srcp = (k0 < 128) ? (g.Ax + (long long)row * 128 + k0 + c * 8)
                          : (g.Aagg + (long long)row * 768 + (k0 - 128) + c * 8);
      else
        srcp = g.Ax + (long long)row * 128 + k0 + c * 8;
      uint4 u = *(const uint4*)srcp;
      ((uint4*)Ah)[r * 8 + (c ^ (r & 7))] = u;
    }
    // ---- stage B: 128 n-rows x 8 col16 units ----
#pragma unroll
    for (int p = 0; p < 4; ++p) {
      int idx = tid + 256 * p;
      int rn = idx >> 3, c = idx & 7;
      uint4 u = *(const uint4*)(Bt + (long long)rn * K + k0 + c * 8);
      ((uint4*)Bh)[rn * 8 + (c ^ (rn & 7))] = u;
    }
    __syncthreads();
    // ---- fragments + MFMA (2 K32 sub-steps) ----
#pragma unroll
    for (int ks = 0; ks < 2; ++ks) {
      half8 a[2], b[4];
#pragma unroll
      for (int fm = 0; fm < 2; ++fm) {
        int row = wm * 32 + fm * 16 + lr;
        a[fm] = *(const half8*)&((uint4*)Ah)[row * 8 + ((ks * 4 + lk) ^ (row & 7))];
      }
#pragma unroll
      for (int fn = 0; fn < 4; ++fn) {
        int col = wn * 64 + fn * 16 + lr;
        b[fn] = *(const half8*)&((uint4*)Bh)[col * 8 + ((ks * 4 + lk) ^ (col & 7))];
      }
#pragma unroll
      for (int fm = 0; fm < 2; ++fm)
#pragma unroll
        for (int fn = 0; fn < 4; ++fn)
          acc[fm][fn] = __builtin_amdgcn_mfma_f32_16x16x32_f16(a[fm], b[fn], acc[fm][fn], 0, 0, 0);
    }
  }

  // ---- epilogue ----
  const float* bias = (MODE == 0) ? g.bias[0] : g.bias[z];
#pragma unroll
  for (int fm = 0; fm < 2; ++fm) {
#pragma unroll
    for (int fn = 0; fn < 4; ++fn) {
      int col = wn * 64 + fn * 16 + lr;
      float bv = bias[col];
#pragma unroll
      for (int j = 0; j < 4; ++j) {
        int row = m0 + wm * 32 + fm * 16 + lk * 4 + j;
        if (row < M) {
          float vv = acc[fm][fn][j] + bv;
          long long off = (long long)row * 128 + col;
          if (MODE == 0) {
            g.h[off] = f2h(vv);
          } else {
            if (z == 0) g.q[off] = vv;
            else if (z == 1) g.kb[off] = f2bf(vv);
            else if (z == 2) g.vb[off] = f2bf(vv);
            else g.sk[off] = vv;
          }
        }
      }
    }
  }
}

// ---------------------------------------------------------------------------
// CSR construction
// ---------------------------------------------------------------------------
__global__ void hist_kernel(const int* __restrict__ dst, int* __restrict__ deg, int E) {
  int e = blockIdx.x * blockDim.x + threadIdx.x;
  if (e < E) atomicAdd(&deg[dst[e]], 1);
}

__launch_bounds__(1024)
__global__ void scan1(const int* __restrict__ deg, int* __restrict__ incl,
                      int* __restrict__ part, int n) {
  __shared__ int sh[1024];
  int tid = threadIdx.x;
  int i = blockIdx.x * 1024 + tid;
  sh[tid] = (i < n) ? deg[i] : 0;
  __syncthreads();
  for (int o = 1; o < 1024; o <<= 1) {
    int t = (tid >= o) ? sh[tid - o] : 0;
    __syncthreads();
    sh[tid] += t;
    __syncthreads();
  }
  if (i < n) incl[i] = sh[tid];
  if (tid == 1023) part[blockIdx.x] = sh[1023];
}

__global__ void scan2(int* part, int nb) {
  if (threadIdx.x == 0 && blockIdx.x == 0) {
    int run = 0;
    for (int b = 0; b < nb; ++b) { int t = part[b]; part[b] = run; run += t; }
  }
}

__global__ void scan3(const int* __restrict__ incl, const int* __restrict__ part,
                      int* __restrict__ offs, int n) {
  int i = blockIdx.x * blockDim.x + threadIdx.x;
  if (i < n) {
    offs[i + 1] = incl[i] + part[i >> 10];
    if (i == 0) offs[0] = 0;
  }
}

__global__ void scatter_kernel(const int* __restrict__ src, const int* __restrict__ dst,
                               const int* __restrict__ etype, const int* __restrict__ offs,
                               int* __restrict__ cur, int* __restrict__ csrc,
                               int* __restrict__ ctyp, int E) {
  int e = blockIdx.x * blockDim.x + threadIdx.x;
  if (e < E) {
    int d = dst[e];
    int p = offs[d] + atomicAdd(&cur[d], 1);
    csrc[p] = src[e];
    ctyp[p] = etype[e];
  }
}

// ---------------------------------------------------------------------------
// RGCN aggregation (aggregate-first, fp16 in / fp16 out):
// agg_h[n][r][:] = mean over r-edges of x_h[src]. One WAVE per node,
// lane owns 2 features (packed fp16 pair). f32 accumulation in registers.
// ---------------------------------------------------------------------------
__launch_bounds__(256)
__global__ void rgcn_agg(const unsigned short* __restrict__ xh, const int* __restrict__ offs,
                         const int* __restrict__ csrc, const int* __restrict__ ctyp,
                         unsigned short* __restrict__ aggh, int N) {
  int node = blockIdx.x * 4 + (threadIdx.x >> 6);
  if (node >= N) return;
  int lane = threadIdx.x & 63;
  int start = offs[node], end = offs[node + 1];

  float a0x = 0.f, a0y = 0.f, a1x = 0.f, a1y = 0.f, a2x = 0.f, a2y = 0.f;
  float a3x = 0.f, a3y = 0.f, a4x = 0.f, a4y = 0.f, a5x = 0.f, a5y = 0.f;
  int c0 = 0, c1 = 0, c2 = 0, c3 = 0, c4 = 0, c5 = 0;

  unsigned xv = 0u;
  if (start < end) {
    int s = csrc[start];
    xv = ((const unsigned*)(xh + (long long)s * FDIM))[lane];
  }
  for (int e = start; e < end; ++e) {
    unsigned cu = xv;
    int r = ctyp[e];
    if (e + 1 < end) {
      int s2 = csrc[e + 1];
      xv = ((const unsigned*)(xh + (long long)s2 * FDIM))[lane];
    }
    union { unsigned u; _Float16 h[2]; } c; c.u = cu;
    float fx = (float)c.h[0], fy = (float)c.h[1];
    switch (r) {
      case 0: a0x += fx; a0y += fy; ++c0; break;
      case 1: a1x += fx; a1y += fy; ++c1; break;
      case 2: a2x += fx; a2y += fy; ++c2; break;
      case 3: a3x += fx; a3y += fy; ++c3; break;
      case 4: a4x += fx; a4y += fy; ++c4; break;
      default: a5x += fx; a5y += fy; ++c5; break;
    }
  }
  float i0 = c0 ? 1.f / (float)c0 : 0.f;
  float i1 = c1 ? 1.f / (float)c1 : 0.f;
  float i2 = c2 ? 1.f / (float)c2 : 0.f;
  float i3 = c3 ? 1.f / (float)c3 : 0.f;
  float i4 = c4 ? 1.f / (float)c4 : 0.f;
  float i5 = c5 ? 1.f / (float)c5 : 0.f;
  unsigned* ap = (unsigned*)(aggh + (long long)node * (NREL * FDIM));
  union { _Float16 h[2]; unsigned u; } p;
#define WR(ri, AX, AY, IV) { p.h[0] = (_Float16)((AX) * (IV)); p.h[1] = (_Float16)((AY) * (IV)); ap[(ri) * 64 + lane] = p.u; }
  WR(0, a0x, a0y, i0) WR(1, a1x, a1y, i1) WR(2, a2x, a2y, i2)
  WR(3, a3x, a3y, i3) WR(4, a4x, a4y, i4) WR(5, a5x, a5y, i5)
#undef WR
}

// ---------------------------------------------------------------------------
// TransformerConv edge-softmax, single-pass online softmax, one WAVE per node.
// k,v bf16; q f32. Butterfly shuffle -> all lanes hold the score.
// ---------------------------------------------------------------------------
__launch_bounds__(256)
__global__ void attn_kernel(const float* __restrict__ q,
                            const unsigned short* __restrict__ kb,
                            const unsigned short* __restrict__ vb,
                            const int* __restrict__ offs, const int* __restrict__ csrc,
                            float* __restrict__ out, int N) {
  int node = blockIdx.x * 4 + (threadIdx.x >> 6);
  if (node >= N) return;
  int lane = threadIdx.x & 63;
  int start = offs[node], end = offs[node + 1];
  if (start >= end) return;  // no incoming edges: attention adds 0

  float2 qf = ((const float2*)(q + (long long)node * FDIM))[lane];
  float m = -INFINITY, den = 0.f, acc0 = 0.f, acc1 = 0.f;

  int s = csrc[start];
  unsigned kk = ((const unsigned*)(kb + (long long)s * FDIM))[lane];
  unsigned vv = ((const unsigned*)(vb + (long long)s * FDIM))[lane];

  for (int e = start; e < end; ++e) {
    unsigned ck = kk, cv = vv;
    if (e + 1 < end) {
      int s2 = csrc[e + 1];
      kk = ((const unsigned*)(kb + (long long)s2 * FDIM))[lane];
      vv = ((const unsigned*)(vb + (long long)s2 * FDIM))[lane];
    }
    float p = qf.x * bf2f(ck & 0xFFFFu) + qf.y * bf2f(ck >> 16);
#pragma unroll
    for (int o = 32; o; o >>= 1) p += __shfl_xor(p, o);
    float sc = p * 0.08838834764831845f;  // 1/sqrt(128)
    float mn = fmaxf(m, sc);
    float scale = __expf(m - mn);  // first edge: exp(-inf) = 0
    float a = __expf(sc - mn);
    den = den * scale + a;
    acc0 = acc0 * scale + a * bf2f(cv & 0xFFFFu);
    acc1 = acc1 * scale + a * bf2f(cv >> 16);
    m = mn;
  }
  float inv = 1.f / den;
  float2* op = (float2*)(out + (long long)node * FDIM);
  float2 o = op[lane];
  o.x += acc0 * inv;
  o.y += acc1 * inv;
  op[lane] = o;
}

// ---------------------------------------------------------------------------
// BatchNorm (training stats) + LeakyReLU
// ---------------------------------------------------------------------------
__launch_bounds__(128)
__global__ void bn_stats(const float* __restrict__ x, float* __restrict__ gsum,
                         float* __restrict__ gsq, int N) {
  int d = threadIdx.x;
  float s = 0.f, qq = 0.f;
  for (int r = blockIdx.x; r < N; r += gridDim.x) {
    float vv = x[(long long)r * FDIM + d];
    s += vv;
    qq += vv * vv;
  }
  atomicAdd(&gsum[d], s);
  atomicAdd(&gsq[d], qq);
}

__global__ void bn_final(const float* __restrict__ gsum, const float* __restrict__ gsq,
                         const float* __restrict__ gamma, const float* __restrict__ beta,
                         float* __restrict__ ss, int N) {
  int d = threadIdx.x;
  if (d < FDIM) {
    float mean = gsum[d] / (float)N;
    float var = gsq[d] / (float)N - mean * mean;
    var = fmaxf(var, 0.f);
    float sc = gamma[d] * rsqrtf(var + 1e-5f);
    ss[d] = sc;
    ss[FDIM + d] = beta[d] - mean * sc;
  }
}

__global__ void bn_apply(float* __restrict__ x, const float* __restrict__ ss, long long total4) {
  long long i = (long long)blockIdx.x * blockDim.x + threadIdx.x;
  if (i < total4) {
    int d0 = (int)((i * 4) & (FDIM - 1));
    float4 vv = ((const float4*)x)[i];
    float y0 = ss[d0 + 0] * vv.x + ss[FDIM + d0 + 0];
    float y1 = ss[d0 + 1] * vv.y + ss[FDIM + d0 + 1];
    float y2 = ss[d0 + 2] * vv.z + ss[FDIM + d0 + 2];
    float y3 = ss[d0 + 3] * vv.w + ss[FDIM + d0 + 3];
    vv.x = (y0 > 0.f) ? y0 : 0.01f * y0;
    vv.y = (y1 > 0.f) ? y1 : 0.01f * y1;
    vv.z = (y2 > 0.f) ? y2 : 0.01f * y2;
    vv.w = (y3 > 0.f) ? y3 : 0.01f * y3;
    ((float4*)x)[i] = vv;
  }
}

// ---------------------------------------------------------------------------
// Launcher
// ---------------------------------------------------------------------------
extern "C" void kernel_launch(void* const* d_in, const int* in_sizes, int n_in,
                              void* d_out, int out_size, void* d_ws, size_t ws_size,
                              hipStream_t stream) {
  const float* x         = (const float*)d_in[0];
  const int*   ei        = (const int*)d_in[1];
  const int*   etype     = (const int*)d_in[2];
  const float* rgcn_w    = (const float*)d_in[3];
  const float* rgcn_root = (const float*)d_in[4];
  const float* rgcn_bias = (const float*)d_in[5];
  const float* wq = (const float*)d_in[6];  const float* bq = (const float*)d_in[7];
  const float* wk = (const float*)d_in[8];  const float* bk = (const float*)d_in[9];
  const float* wv = (const float*)d_in[10]; const float* bv = (const float*)d_in[11];
  const float* wsk = (const float*)d_in[12]; const float* bsk = (const float*)d_in[13];
  const float* gamma = (const float*)d_in[14]; const float* beta = (const float*)d_in[15];

  const int N = in_sizes[0] / FDIM;
  const int E = in_sizes[1] / 2;
  const int* src = ei;
  const int* dst = ei + E;

  // ---- workspace layout (byte-offset, 256B-aligned chunks) ----
  char* base = (char*)d_ws;
  size_t off = 0;
  auto alloc = [&](size_t bytes) -> char* {
    char* p = base + off;
    off += (bytes + 255) & ~(size_t)255;
    return p;
  };
  unsigned short* aggh = (unsigned short*)alloc((size_t)N * (NREL * FDIM) * 2);  // 76.8MB
  // q/k/v reuse the agg region after the RGCN GEMM consumes it:
  float*          qb   = (float*)aggh;                                            // N*128 f32
  unsigned short* kbuf = (unsigned short*)((char*)aggh + (size_t)N * FDIM * 4);   // N*128 bf16
  unsigned short* vbuf = kbuf + (size_t)N * FDIM;                                 // N*128 bf16
  unsigned short* xh   = (unsigned short*)alloc((size_t)N * FDIM * 2);
  unsigned short* hh   = (unsigned short*)alloc((size_t)N * FDIM * 2);
  unsigned short* btR  = (unsigned short*)alloc((size_t)896 * 128 * 2);
  unsigned short* btQ  = (unsigned short*)alloc((size_t)4 * 128 * 128 * 2);
  int* deg  = (int*)alloc((size_t)2 * N * 4);           // deg + cur (contiguous)
  int* cur  = deg + N;
  int* offs = (int*)alloc((size_t)(N + 1) * 4);
  int* incl = (int*)alloc((size_t)N * 4);
  int* part = (int*)alloc((size_t)64 * 4);
  int* csrc = (int*)alloc((size_t)E * 4);
  int* ctyp = (int*)alloc((size_t)E * 4);
  float* gsum = (float*)alloc((size_t)(128 + 128 + 256) * 4);
  float* gsq  = gsum + FDIM;
  float* ss   = gsum + 2 * FDIM;

  float* out = (float*)d_out;

  hipMemsetAsync(deg, 0, (size_t)2 * N * sizeof(int), stream);        // deg + cur
  hipMemsetAsync(gsum, 0, (size_t)2 * FDIM * sizeof(float), stream);  // gsum + gsq

  // ---- conversions ----
  int n4 = N * FDIM / 4;
  cvt_x_kernel<<<(n4 + 255) / 256, 256, 0, stream>>>(x, xh, n4);
  cvt_wr_kernel<<<(896 * 128 + 255) / 256, 256, 0, stream>>>(rgcn_root, rgcn_w, btR);
  WPtrs wp; wp.W[0] = wq; wp.W[1] = wk; wp.W[2] = wv; wp.W[3] = wsk;
  cvt_wq_kernel<<<(4 * 128 * 128 + 255) / 256, 256, 0, stream>>>(wp, btQ);

  // ---- CSR build (by dst) ----
  hist_kernel<<<(E + 255) / 256, 256, 0, stream>>>(dst, deg, E);
  int nb = (N + 1023) / 1024;
  scan1<<<nb, 1024, 0, stream>>>(deg, incl, part, N);
  scan2<<<1, 64, 0, stream>>>(part, nb);
  scan3<<<(N + 255) / 256, 256, 0, stream>>>(incl, part, offs, N);
  scatter_kernel<<<(E + 255) / 256, 256, 0, stream>>>(src, dst, etype, offs, cur, csrc, ctyp, E);

  const int nodeBlocks = (N + 3) / 4;
  const int gemmBlocks = (N + 63) / 64;

  // ---- RGCN: aggregate-first (fp16), then fused K=896 MFMA GEMM -> h (fp16) ----
  rgcn_agg<<<nodeBlocks, 256, 0, stream>>>(xh, offs, csrc, ctyp, aggh, N);

  GArgs g0 = {};
  g0.Ax = xh; g0.Aagg = aggh; g0.Bt = btR;
  g0.bias[0] = rgcn_bias;
  g0.h = hh; g0.M = N; g0.K = 896;
  gemm_mfma<0><<<dim3(gemmBlocks, 1, 1), 256, 0, stream>>>(g0);

  // ---- q,k,v,skip projections (z=4), k/v bf16, q f32, skip f32 into out ----
  GArgs g1 = {};
  g1.Ax = hh; g1.Bt = btQ;
  g1.bias[0] = bq; g1.bias[1] = bk; g1.bias[2] = bv; g1.bias[3] = bsk;
  g1.q = qb; g1.kb = kbuf; g1.vb = vbuf; g1.sk = out;
  g1.M = N; g1.K = 128;
  gemm_mfma<1><<<dim3(gemmBlocks, 1, 4), 256, 0, stream>>>(g1);

  // ---- edge-softmax attention (accumulates into out) ----
  attn_kernel<<<nodeBlocks, 256, 0, stream>>>(qb, kbuf, vbuf, offs, csrc, out, N);

  // ---- BatchNorm (training stats) + LeakyReLU, in place on out ----
  bn_stats<<<512, 128, 0, stream>>>(out, gsum, gsq, N);
  bn_final<<<1, 128, 0, stream>>>(gsum, gsq, gamma, beta, ss, N);
  long long total4 = (long long)N * FDIM / 4;
  bn_apply<<<(int)((total4 + 255) / 256), 256, 0, stream>>>(out, ss, total4);
}

// Round 6
// 400.581 us; speedup vs baseline: 1.8828x; 1.1229x over previous
//
#include <hip/hip_runtime.h>
#include <hip/hip_bf16.h>
#include <math.h>

#define FDIM 128
#define NREL 6

typedef _Float16 half8 __attribute__((ext_vector_type(8)));
typedef float f32x4 __attribute__((ext_vector_type(4)));

// ---------------- bf16 helpers (OCP bf16 = top 16 bits of f32, RNE) --------
static __device__ __forceinline__ unsigned short f2bf(float f) {
  union { float f; unsigned u; } v; v.f = f;
  unsigned r = v.u + 0x7FFFu + ((v.u >> 16) & 1u);
  return (unsigned short)(r >> 16);
}
static __device__ __forceinline__ float bf2f(unsigned us) {
  union { unsigned u; float f; } v; v.u = us << 16; return v.f;
}
// ---------------- fp16 helpers ----------------------------------------------
static __device__ __forceinline__ unsigned short f2h(float f) {
  union { _Float16 h; unsigned short u; } p; p.h = (_Float16)f; return p.u;
}

// ---------------------------------------------------------------------------
// dtype conversion passes
// ---------------------------------------------------------------------------
__global__ void cvt_x_kernel(const float* __restrict__ x, unsigned short* __restrict__ xh,
                             int n4) {
  int i = blockIdx.x * 256 + threadIdx.x;
  if (i < n4) {
    float4 v = ((const float4*)x)[i];
    union { _Float16 h[4]; uint2 u; } p;
    p.h[0] = (_Float16)v.x; p.h[1] = (_Float16)v.y;
    p.h[2] = (_Float16)v.z; p.h[3] = (_Float16)v.w;
    ((uint2*)xh)[i] = p.u;
  }
}

// Bt_rgcn[n][kk] (n<128, kk<896) = (kk<128 ? root[kk][n] : w[kk-128][n]) as fp16
__global__ void cvt_wr_kernel(const float* __restrict__ root, const float* __restrict__ w,
                              unsigned short* __restrict__ bt) {
  int i = blockIdx.x * 256 + threadIdx.x;
  if (i < 896 * 128) {
    int n = i / 896, kk = i - n * 896;
    float v = (kk < 128) ? root[kk * 128 + n] : w[(long long)(kk - 128) * 128 + n];
    bt[i] = f2h(v);
  }
}

// Bt_qkvs[z][n][kk] = W_z[kk][n] as fp16
struct WPtrs { const float* W[4]; };
__global__ void cvt_wq_kernel(WPtrs wp, unsigned short* __restrict__ bt) {
  int i = blockIdx.x * 256 + threadIdx.x;
  if (i < 4 * 128 * 128) {
    int z = i >> 14;
    int r = i & 16383;
    int n = r >> 7, kk = r & 127;
    bt[i] = f2h(wp.W[z][kk * 128 + n]);
  }
}

// ---------------------------------------------------------------------------
// fp16 MFMA GEMM, tile 64(M) x 128(N), BK=64, 256 thr = 4 waves (2M x 2N).
// XOR-swizzled LDS (T2); B pre-transposed [z][128(n)][K] fp16.
// ---------------------------------------------------------------------------
struct GArgs {
  const unsigned short* Ax;    // fp16 [M][128]  (x_h or h_h)
  const unsigned short* Aagg;  // fp16 [M][768]  (MODE0)
  const unsigned short* Bt;    // fp16 [z][128][K]
  const float* bias[4];
  float* q; unsigned short* kb; unsigned short* vb; float* sk;  // MODE1 outputs
  unsigned short* h;                                            // MODE0 output
  int M, K;
};

template <int MODE>
__launch_bounds__(256)
__global__ void gemm_mfma(GArgs g) {
  __shared__ unsigned short Ah[64 * 64];    // [r][8 x 16B units], swizzled
  __shared__ unsigned short Bh[128 * 64];   // [n][8 x 16B units], swizzled
  const int tid = threadIdx.x;
  const int lane = tid & 63;
  const int wid = tid >> 6;
  const int wm = wid >> 1, wn = wid & 1;
  const int lr = lane & 15, lk = lane >> 4;
  const int m0 = blockIdx.x * 64;
  const int z = (MODE == 1) ? blockIdx.z : 0;
  const unsigned short* Bt = g.Bt + (long long)z * 128 * g.K;
  const int K = g.K;
  const int M = g.M;

  f32x4 acc[2][4];
#pragma unroll
  for (int a = 0; a < 2; ++a)
#pragma unroll
    for (int b = 0; b < 4; ++b) { acc[a][b][0] = 0.f; acc[a][b][1] = 0.f; acc[a][b][2] = 0.f; acc[a][b][3] = 0.f; }

  for (int k0 = 0; k0 < K; k0 += 64) {
    __syncthreads();
    // ---- stage A: 64 rows x 8 col16 units ----
#pragma unroll
    for (int p = 0; p < 2; ++p) {
      int idx = tid + 256 * p;
      int r = idx >> 3, c = idx & 7;
      int row = m0 + r; if (row > M - 1) row = M - 1;   // clamp tail (store guarded)
      const unsigned short* srcp;
      if (MODE == 0)
        srcp = (k0 < 128) ? (g.Ax + (long long)row * 128 + k0 + c * 8)
                          : (g.Aagg + (long long)row * 768 + (k0 - 128) + c * 8);
      else
        srcp = g.Ax + (long long)row * 128 + k0 + c * 8;
      uint4 u = *(const uint4*)srcp;
      ((uint4*)Ah)[r * 8 + (c ^ (r & 7))] = u;
    }
    // ---- stage B: 128 n-rows x 8 col16 units ----
#pragma unroll
    for (int p = 0; p < 4; ++p) {
      int idx = tid + 256 * p;
      int rn = idx >> 3, c = idx & 7;
      uint4 u = *(const uint4*)(Bt + (long long)rn * K + k0 + c * 8);
      ((uint4*)Bh)[rn * 8 + (c ^ (rn & 7))] = u;
    }
    __syncthreads();
    // ---- fragments + MFMA (2 K32 sub-steps) ----
#pragma unroll
    for (int ks = 0; ks < 2; ++ks) {
      half8 a[2], b[4];
#pragma unroll
      for (int fm = 0; fm < 2; ++fm) {
        int row = wm * 32 + fm * 16 + lr;
        a[fm] = *(const half8*)&((uint4*)Ah)[row * 8 + ((ks * 4 + lk) ^ (row & 7))];
      }
#pragma unroll
      for (int fn = 0; fn < 4; ++fn) {
        int col = wn * 64 + fn * 16 + lr;
        b[fn] = *(const half8*)&((uint4*)Bh)[col * 8 + ((ks * 4 + lk) ^ (col & 7))];
      }
#pragma unroll
      for (int fm = 0; fm < 2; ++fm)
#pragma unroll
        for (int fn = 0; fn < 4; ++fn)
          acc[fm][fn] = __builtin_amdgcn_mfma_f32_16x16x32_f16(a[fm], b[fn], acc[fm][fn], 0, 0, 0);
    }
  }

  // ---- epilogue ----
  const float* bias = (MODE == 0) ? g.bias[0] : g.bias[z];
#pragma unroll
  for (int fm = 0; fm < 2; ++fm) {
#pragma unroll
    for (int fn = 0; fn < 4; ++fn) {
      int col = wn * 64 + fn * 16 + lr;
      float bv = bias[col];
#pragma unroll
      for (int j = 0; j < 4; ++j) {
        int row = m0 + wm * 32 + fm * 16 + lk * 4 + j;
        if (row < M) {
          float vv = acc[fm][fn][j] + bv;
          long long off = (long long)row * 128 + col;
          if (MODE == 0) {
            g.h[off] = f2h(vv);
          } else {
            if (z == 0) g.q[off] = vv;
            else if (z == 1) g.kb[off] = f2bf(vv);
            else if (z == 2) g.vb[off] = f2bf(vv);
            else g.sk[off] = vv;
          }
        }
      }
    }
  }
}

// ---------------------------------------------------------------------------
// CSR construction
// ---------------------------------------------------------------------------
__global__ void hist_kernel(const int* __restrict__ dst, int* __restrict__ deg, int E) {
  int e = blockIdx.x * blockDim.x + threadIdx.x;
  if (e < E) atomicAdd(&deg[dst[e]], 1);
}

__launch_bounds__(1024)
__global__ void scan1(const int* __restrict__ deg, int* __restrict__ incl,
                      int* __restrict__ part, int n) {
  __shared__ int sh[1024];
  int tid = threadIdx.x;
  int i = blockIdx.x * 1024 + tid;
  sh[tid] = (i < n) ? deg[i] : 0;
  __syncthreads();
  for (int o = 1; o < 1024; o <<= 1) {
    int t = (tid >= o) ? sh[tid - o] : 0;
    __syncthreads();
    sh[tid] += t;
    __syncthreads();
  }
  if (i < n) incl[i] = sh[tid];
  if (tid == 1023) part[blockIdx.x] = sh[1023];
}

__global__ void scan2(int* part, int nb) {
  if (threadIdx.x == 0 && blockIdx.x == 0) {
    int run = 0;
    for (int b = 0; b < nb; ++b) { int t = part[b]; part[b] = run; run += t; }
  }
}

__global__ void scan3(const int* __restrict__ incl, const int* __restrict__ part,
                      int* __restrict__ offs, int n) {
  int i = blockIdx.x * blockDim.x + threadIdx.x;
  if (i < n) {
    offs[i + 1] = incl[i] + part[i >> 10];
    if (i == 0) offs[0] = 0;
  }
}

__global__ void scatter_kernel(const int* __restrict__ src, const int* __restrict__ dst,
                               const int* __restrict__ etype, const int* __restrict__ offs,
                               int* __restrict__ cur, int* __restrict__ csrc,
                               int* __restrict__ ctyp, int E) {
  int e = blockIdx.x * blockDim.x + threadIdx.x;
  if (e < E) {
    int d = dst[e];
    int p = offs[d] + atomicAdd(&cur[d], 1);
    csrc[p] = src[e];
    ctyp[p] = etype[e];
  }
}

// ---------------------------------------------------------------------------
// RGCN aggregation (aggregate-first, fp16 in / fp16 out), one WAVE per node.
// 4-edge unrolled chunks -> 4 gathers in flight; scalar (readfirstlane) switch.
// ---------------------------------------------------------------------------
__launch_bounds__(256)
__global__ void rgcn_agg(const unsigned short* __restrict__ xh, const int* __restrict__ offs,
                         const int* __restrict__ csrc, const int* __restrict__ ctyp,
                         unsigned short* __restrict__ aggh, int N) {
  int node = blockIdx.x * 4 + (threadIdx.x >> 6);
  if (node >= N) return;
  int lane = threadIdx.x & 63;
  int start = offs[node], end = offs[node + 1];

  float a0x = 0.f, a0y = 0.f, a1x = 0.f, a1y = 0.f, a2x = 0.f, a2y = 0.f;
  float a3x = 0.f, a3y = 0.f, a4x = 0.f, a4y = 0.f, a5x = 0.f, a5y = 0.f;
  int c0 = 0, c1 = 0, c2 = 0, c3 = 0, c4 = 0, c5 = 0;

#define ACC(T, XU)                                                         \
  {                                                                        \
    union { unsigned u; _Float16 h[2]; } cc; cc.u = (XU);                  \
    float fx = (float)cc.h[0], fy = (float)cc.h[1];                        \
    switch (T) {                                                           \
      case 0: a0x += fx; a0y += fy; ++c0; break;                           \
      case 1: a1x += fx; a1y += fy; ++c1; break;                           \
      case 2: a2x += fx; a2y += fy; ++c2; break;                           \
      case 3: a3x += fx; a3y += fy; ++c3; break;                           \
      case 4: a4x += fx; a4y += fy; ++c4; break;                           \
      default: a5x += fx; a5y += fy; ++c5; break;                          \
    }                                                                      \
  }

  int e = start;
  for (; e + 4 <= end; e += 4) {
    int s0 = csrc[e], s1 = csrc[e + 1], s2 = csrc[e + 2], s3 = csrc[e + 3];
    int t0 = __builtin_amdgcn_readfirstlane(ctyp[e]);
    int t1 = __builtin_amdgcn_readfirstlane(ctyp[e + 1]);
    int t2 = __builtin_amdgcn_readfirstlane(ctyp[e + 2]);
    int t3 = __builtin_amdgcn_readfirstlane(ctyp[e + 3]);
    unsigned x0 = ((const unsigned*)(xh + (long long)s0 * FDIM))[lane];
    unsigned x1 = ((const unsigned*)(xh + (long long)s1 * FDIM))[lane];
    unsigned x2 = ((const unsigned*)(xh + (long long)s2 * FDIM))[lane];
    unsigned x3 = ((const unsigned*)(xh + (long long)s3 * FDIM))[lane];
    ACC(t0, x0) ACC(t1, x1) ACC(t2, x2) ACC(t3, x3)
  }
  for (; e < end; ++e) {
    int s0 = csrc[e];
    int t0 = __builtin_amdgcn_readfirstlane(ctyp[e]);
    unsigned x0 = ((const unsigned*)(xh + (long long)s0 * FDIM))[lane];
    ACC(t0, x0)
  }
#undef ACC

  float i0 = c0 ? 1.f / (float)c0 : 0.f;
  float i1 = c1 ? 1.f / (float)c1 : 0.f;
  float i2 = c2 ? 1.f / (float)c2 : 0.f;
  float i3 = c3 ? 1.f / (float)c3 : 0.f;
  float i4 = c4 ? 1.f / (float)c4 : 0.f;
  float i5 = c5 ? 1.f / (float)c5 : 0.f;
  unsigned* ap = (unsigned*)(aggh + (long long)node * (NREL * FDIM));
  union { _Float16 h[2]; unsigned u; } p;
#define WR(ri, AX, AY, IV) { p.h[0] = (_Float16)((AX) * (IV)); p.h[1] = (_Float16)((AY) * (IV)); ap[(ri) * 64 + lane] = p.u; }
  WR(0, a0x, a0y, i0) WR(1, a1x, a1y, i1) WR(2, a2x, a2y, i2)
  WR(3, a3x, a3y, i3) WR(4, a4x, a4y, i4) WR(5, a5x, a5y, i5)
#undef WR
}

// ---------------------------------------------------------------------------
// TransformerConv edge-softmax, one WAVE per node, EDGE-PAIR processing:
// lanes 0-31 dot edge e (4 feats/lane), lanes 32-63 edge e+1. 5 xor-shuffles
// reduce both edges at once; 1 cross-shuffle exchanges scores. Log2-domain
// online softmax (scale folded into q) -> exp2f = native v_exp_f32.
// 1-pair-ahead software pipeline (6 loads in flight).
// ---------------------------------------------------------------------------
__launch_bounds__(256)
__global__ void attn_kernel(const float* __restrict__ q,
                            const unsigned short* __restrict__ kb,
                            const unsigned short* __restrict__ vb,
                            const int* __restrict__ offs, const int* __restrict__ csrc,
                            float* __restrict__ out, int N) {
  int node = blockIdx.x * 4 + (threadIdx.x >> 6);
  if (node >= N) return;
  int lane = threadIdx.x & 63;
  int start = offs[node], end = offs[node + 1];
  if (start >= end) return;  // no incoming edges: attention adds 0

  // q fragment for the dot: 4 feats/lane, same for both halves.
  const float C = 0.08838834764831845f * 1.4426950408889634f;  // 1/sqrt(128) * log2(e)
  float4 qd = *(const float4*)(q + (long long)node * FDIM + 4 * (lane & 31));
  qd.x *= C; qd.y *= C; qd.z *= C; qd.w *= C;
  const bool hiHalf = (lane >= 32);

  float m = -INFINITY, den = 0.f, acc0 = 0.f, acc1 = 0.f;

  const int npairs = (end - start + 1) >> 1;

#define LOADP(P, K2, V0, V1, INV)                                           \
  {                                                                         \
    int e0 = start + 2 * (P);                                               \
    int s0 = csrc[e0];                                                      \
    bool val = (e0 + 1 < end);                                              \
    int s1 = val ? csrc[e0 + 1] : s0;                                       \
    INV = val ? 0 : 1;                                                      \
    int sh = hiHalf ? s1 : s0;                                              \
    K2 = *(const uint2*)(kb + (long long)sh * FDIM + 4 * (lane & 31));      \
    V0 = ((const unsigned*)(vb + (long long)s0 * FDIM))[lane];              \
    V1 = ((const unsigned*)(vb + (long long)s1 * FDIM))[lane];              \
  }

  uint2 kA; unsigned vA0, vA1; int invA;
  LOADP(0, kA, vA0, vA1, invA)

  for (int p = 0; p < npairs; ++p) {
    uint2 kB; unsigned vB0, vB1; int invB;
    bool more = (p + 1 < npairs);
    if (more) LOADP(p + 1, kB, vB0, vB1, invB)

    // ---- dot (both edges at once) ----
    float pd = qd.x * bf2f(kA.x & 0xFFFFu) + qd.y * bf2f(kA.x >> 16) +
               qd.z * bf2f(kA.y & 0xFFFFu) + qd.w * bf2f(kA.y >> 16);
#pragma unroll
    for (int o = 1; o <= 16; o <<= 1) pd += __shfl_xor(pd, o);
    float cross = __shfl_xor(pd, 32);
    float sc0 = hiHalf ? cross : pd;     // score(e)   [log2 domain]
    float sc1 = hiHalf ? pd : cross;     // score(e+1)
    if (invA) sc1 = -INFINITY;           // odd tail -> weight exp2's to 0

    // ---- online softmax update (2 edges) ----
    float mn = fmaxf(m, fmaxf(sc0, sc1));
    float scl = exp2f(m - mn);           // first pair: exp2(-inf)=0
    float a0 = exp2f(sc0 - mn);
    float a1 = exp2f(sc1 - mn);
    den = den * scl + a0 + a1;
    acc0 = acc0 * scl + a0 * bf2f(vA0 & 0xFFFFu) + a1 * bf2f(vA1 & 0xFFFFu);
    acc1 = acc1 * scl + a0 * bf2f(vA0 >> 16) + a1 * bf2f(vA1 >> 16);
    m = mn;

    if (more) { kA = kB; vA0 = vB0; vA1 = vB1; invA = invB; }
  }
#undef LOADP

  float inv = 1.f / den;
  float2* op = (float2*)(out + (long long)node * FDIM);
  float2 o = op[lane];
  o.x += acc0 * inv;
  o.y += acc1 * inv;
  op[lane] = o;
}

// ---------------------------------------------------------------------------
// BatchNorm (training stats) + LeakyReLU
// ---------------------------------------------------------------------------
__launch_bounds__(128)
__global__ void bn_stats(const float* __restrict__ x, float* __restrict__ gsum,
                         float* __restrict__ gsq, int N) {
  int d = threadIdx.x;
  float s = 0.f, qq = 0.f;
  for (int r = blockIdx.x; r < N; r += gridDim.x) {
    float vv = x[(long long)r * FDIM + d];
    s += vv;
    qq += vv * vv;
  }
  atomicAdd(&gsum[d], s);
  atomicAdd(&gsq[d], qq);
}

__global__ void bn_final(const float* __restrict__ gsum, const float* __restrict__ gsq,
                         const float* __restrict__ gamma, const float* __restrict__ beta,
                         float* __restrict__ ss, int N) {
  int d = threadIdx.x;
  if (d < FDIM) {
    float mean = gsum[d] / (float)N;
    float var = gsq[d] / (float)N - mean * mean;
    var = fmaxf(var, 0.f);
    float sc = gamma[d] * rsqrtf(var + 1e-5f);
    ss[d] = sc;
    ss[FDIM + d] = beta[d] - mean * sc;
  }
}

__global__ void bn_apply(float* __restrict__ x, const float* __restrict__ ss, long long total4) {
  long long i = (long long)blockIdx.x * blockDim.x + threadIdx.x;
  if (i < total4) {
    int d0 = (int)((i * 4) & (FDIM - 1));
    float4 vv = ((const float4*)x)[i];
    float y0 = ss[d0 + 0] * vv.x + ss[FDIM + d0 + 0];
    float y1 = ss[d0 + 1] * vv.y + ss[FDIM + d0 + 1];
    float y2 = ss[d0 + 2] * vv.z + ss[FDIM + d0 + 2];
    float y3 = ss[d0 + 3] * vv.w + ss[FDIM + d0 + 3];
    vv.x = (y0 > 0.f) ? y0 : 0.01f * y0;
    vv.y = (y1 > 0.f) ? y1 : 0.01f * y1;
    vv.z = (y2 > 0.f) ? y2 : 0.01f * y2;
    vv.w = (y3 > 0.f) ? y3 : 0.01f * y3;
    ((float4*)x)[i] = vv;
  }
}

// ---------------------------------------------------------------------------
// Launcher
// ---------------------------------------------------------------------------
extern "C" void kernel_launch(void* const* d_in, const int* in_sizes, int n_in,
                              void* d_out, int out_size, void* d_ws, size_t ws_size,
                              hipStream_t stream) {
  const float* x         = (const float*)d_in[0];
  const int*   ei        = (const int*)d_in[1];
  const int*   etype     = (const int*)d_in[2];
  const float* rgcn_w    = (const float*)d_in[3];
  const float* rgcn_root = (const float*)d_in[4];
  const float* rgcn_bias = (const float*)d_in[5];
  const float* wq = (const float*)d_in[6];  const float* bq = (const float*)d_in[7];
  const float* wk = (const float*)d_in[8];  const float* bk = (const float*)d_in[9];
  const float* wv = (const float*)d_in[10]; const float* bv = (const float*)d_in[11];
  const float* wsk = (const float*)d_in[12]; const float* bsk = (const float*)d_in[13];
  const float* gamma = (const float*)d_in[14]; const float* beta = (const float*)d_in[15];

  const int N = in_sizes[0] / FDIM;
  const int E = in_sizes[1] / 2;
  const int* src = ei;
  const int* dst = ei + E;

  // ---- workspace layout (byte-offset, 256B-aligned chunks) ----
  char* base = (char*)d_ws;
  size_t off = 0;
  auto alloc = [&](size_t bytes) -> char* {
    char* p = base + off;
    off += (bytes + 255) & ~(size_t)255;
    return p;
  };
  unsigned short* aggh = (unsigned short*)alloc((size_t)N * (NREL * FDIM) * 2);  // 76.8MB
  // q/k/v reuse the agg region after the RGCN GEMM consumes it:
  float*          qb   = (float*)aggh;                                            // N*128 f32
  unsigned short* kbuf = (unsigned short*)((char*)aggh + (size_t)N * FDIM * 4);   // N*128 bf16
  unsigned short* vbuf = kbuf + (size_t)N * FDIM;                                 // N*128 bf16
  unsigned short* xh   = (unsigned short*)alloc((size_t)N * FDIM * 2);
  unsigned short* hh   = (unsigned short*)alloc((size_t)N * FDIM * 2);
  unsigned short* btR  = (unsigned short*)alloc((size_t)896 * 128 * 2);
  unsigned short* btQ  = (unsigned short*)alloc((size_t)4 * 128 * 128 * 2);
  int* deg  = (int*)alloc((size_t)2 * N * 4);           // deg + cur (contiguous)
  int* cur  = deg + N;
  int* offs = (int*)alloc((size_t)(N + 1) * 4);
  int* incl = (int*)alloc((size_t)N * 4);
  int* part = (int*)alloc((size_t)64 * 4);
  int* csrc = (int*)alloc((size_t)E * 4);
  int* ctyp = (int*)alloc((size_t)E * 4);
  float* gsum = (float*)alloc((size_t)(128 + 128 + 256) * 4);
  float* gsq  = gsum + FDIM;
  float* ss   = gsum + 2 * FDIM;

  float* out = (float*)d_out;

  hipMemsetAsync(deg, 0, (size_t)2 * N * sizeof(int), stream);        // deg + cur
  hipMemsetAsync(gsum, 0, (size_t)2 * FDIM * sizeof(float), stream);  // gsum + gsq

  // ---- conversions ----
  int n4 = N * FDIM / 4;
  cvt_x_kernel<<<(n4 + 255) / 256, 256, 0, stream>>>(x, xh, n4);
  cvt_wr_kernel<<<(896 * 128 + 255) / 256, 256, 0, stream>>>(rgcn_root, rgcn_w, btR);
  WPtrs wp; wp.W[0] = wq; wp.W[1] = wk; wp.W[2] = wv; wp.W[3] = wsk;
  cvt_wq_kernel<<<(4 * 128 * 128 + 255) / 256, 256, 0, stream>>>(wp, btQ);

  // ---- CSR build (by dst) ----
  hist_kernel<<<(E + 255) / 256, 256, 0, stream>>>(dst, deg, E);
  int nb = (N + 1023) / 1024;
  scan1<<<nb, 1024, 0, stream>>>(deg, incl, part, N);
  scan2<<<1, 64, 0, stream>>>(part, nb);
  scan3<<<(N + 255) / 256, 256, 0, stream>>>(incl, part, offs, N);
  scatter_kernel<<<(E + 255) / 256, 256, 0, stream>>>(src, dst, etype, offs, cur, csrc, ctyp, E);

  const int nodeBlocks = (N + 3) / 4;
  const int gemmBlocks = (N + 63) / 64;

  // ---- RGCN: aggregate-first (fp16), then fused K=896 MFMA GEMM -> h (fp16) ----
  rgcn_agg<<<nodeBlocks, 256, 0, stream>>>(xh, offs, csrc, ctyp, aggh, N);

  GArgs g0 = {};
  g0.Ax = xh; g0.Aagg = aggh; g0.Bt = btR;
  g0.bias[0] = rgcn_bias;
  g0.h = hh; g0.M = N; g0.K = 896;
  gemm_mfma<0><<<dim3(gemmBlocks, 1, 1), 256, 0, stream>>>(g0);

  // ---- q,k,v,skip projections (z=4), k/v bf16, q f32, skip f32 into out ----
  GArgs g1 = {};
  g1.Ax = hh; g1.Bt = btQ;
  g1.bias[0] = bq; g1.bias[1] = bk; g1.bias[2] = bv; g1.bias[3] = bsk;
  g1.q = qb; g1.kb = kbuf; g1.vb = vbuf; g1.sk = out;
  g1.M = N; g1.K = 128;
  gemm_mfma<1><<<dim3(gemmBlocks, 1, 4), 256, 0, stream>>>(g1);

  // ---- edge-softmax attention (accumulates into out) ----
  attn_kernel<<<nodeBlocks, 256, 0, stream>>>(qb, kbuf, vbuf, offs, csrc, out, N);

  // ---- BatchNorm (training stats) + LeakyReLU, in place on out ----
  bn_stats<<<512, 128, 0, stream>>>(out, gsum, gsq, N);
  bn_final<<<1, 128, 0, stream>>>(gsum, gsq, gamma, beta, ss, N);
  long long total4 = (long long)N * FDIM / 4;
  bn_apply<<<(int)((total4 + 255) / 256), 256, 0, stream>>>(out, ss, total4);
}

// Round 7
// 356.428 us; speedup vs baseline: 2.1161x; 1.1239x over previous
//
#include <hip/hip_runtime.h>
#include <hip/hip_bf16.h>
#include <math.h>

#define FDIM 128
#define NREL 6

typedef _Float16 half8 __attribute__((ext_vector_type(8)));
typedef _Float16 h16x2 __attribute__((ext_vector_type(2)));
typedef float f32x4 __attribute__((ext_vector_type(4)));

#if __has_builtin(__builtin_amdgcn_fdot2)
#define FDOT2(A, B, C) __builtin_amdgcn_fdot2((A), (B), (C), false)
#else
#define FDOT2(A, B, C) ((float)(A)[0] * (float)(B)[0] + ((float)(A)[1] * (float)(B)[1] + (C)))
#endif

// ---------------- fp16 helpers ----------------------------------------------
static __device__ __forceinline__ unsigned short f2h(float f) {
  union { _Float16 h; unsigned short u; } p; p.h = (_Float16)f; return p.u;
}

// ---------------------------------------------------------------------------
// dtype conversion passes
// ---------------------------------------------------------------------------
__global__ void cvt_x_kernel(const float* __restrict__ x, unsigned short* __restrict__ xh,
                             int n4) {
  int i = blockIdx.x * 256 + threadIdx.x;
  if (i < n4) {
    float4 v = ((const float4*)x)[i];
    union { _Float16 h[4]; uint2 u; } p;
    p.h[0] = (_Float16)v.x; p.h[1] = (_Float16)v.y;
    p.h[2] = (_Float16)v.z; p.h[3] = (_Float16)v.w;
    ((uint2*)xh)[i] = p.u;
  }
}

// Bt_rgcn[n][kk] (n<128, kk<896) = (kk<128 ? root[kk][n] : w[kk-128][n]) as fp16
__global__ void cvt_wr_kernel(const float* __restrict__ root, const float* __restrict__ w,
                              unsigned short* __restrict__ bt) {
  int i = blockIdx.x * 256 + threadIdx.x;
  if (i < 896 * 128) {
    int n = i / 896, kk = i - n * 896;
    float v = (kk < 128) ? root[kk * 128 + n] : w[(long long)(kk - 128) * 128 + n];
    bt[i] = f2h(v);
  }
}

// Bt_qkvs[z][n][kk] = W_z[kk][n] as fp16
struct WPtrs { const float* W[4]; };
__global__ void cvt_wq_kernel(WPtrs wp, unsigned short* __restrict__ bt) {
  int i = blockIdx.x * 256 + threadIdx.x;
  if (i < 4 * 128 * 128) {
    int z = i >> 14;
    int r = i & 16383;
    int n = r >> 7, kk = r & 127;
    bt[i] = f2h(wp.W[z][kk * 128 + n]);
  }
}

// ---------------------------------------------------------------------------
// fp16 MFMA GEMM, tile 64(M) x 128(N), BK=64, 256 thr = 4 waves (2M x 2N).
// XOR-swizzled LDS (T2); B pre-transposed [z][128(n)][K] fp16.
// MODE1 outputs q (fp16, score-scale pre-folded), k (fp16), v (fp16), skip(f32).
// ---------------------------------------------------------------------------
struct GArgs {
  const unsigned short* Ax;    // fp16 [M][128]  (x_h or h_h)
  const unsigned short* Aagg;  // fp16 [M][768]  (MODE0)
  const unsigned short* Bt;    // fp16 [z][128][K]
  const float* bias[4];
  unsigned short* qh; unsigned short* kh; unsigned short* vh; float* sk;  // MODE1
  unsigned short* h;                                                      // MODE0
  int M, K;
};

template <int MODE>
__launch_bounds__(256)
__global__ void gemm_mfma(GArgs g) {
  __shared__ unsigned short Ah[64 * 64];    // [r][8 x 16B units], swizzled
  __shared__ unsigned short Bh[128 * 64];   // [n][8 x 16B units], swizzled
  const int tid = threadIdx.x;
  const int lane = tid & 63;
  const int wid = tid >> 6;
  const int wm = wid >> 1, wn = wid & 1;
  const int lr = lane & 15, lk = lane >> 4;
  const int m0 = blockIdx.x * 64;
  const int z = (MODE == 1) ? blockIdx.z : 0;
  const unsigned short* Bt = g.Bt + (long long)z * 128 * g.K;
  const int K = g.K;
  const int M = g.M;

  f32x4 acc[2][4];
#pragma unroll
  for (int a = 0; a < 2; ++a)
#pragma unroll
    for (int b = 0; b < 4; ++b) { acc[a][b][0] = 0.f; acc[a][b][1] = 0.f; acc[a][b][2] = 0.f; acc[a][b][3] = 0.f; }

  for (int k0 = 0; k0 < K; k0 += 64) {
    __syncthreads();
    // ---- stage A: 64 rows x 8 col16 units ----
#pragma unroll
    for (int p = 0; p < 2; ++p) {
      int idx = tid + 256 * p;
      int r = idx >> 3, c = idx & 7;
      int row = m0 + r; if (row > M - 1) row = M - 1;   // clamp tail (store guarded)
      const unsigned short* srcp;
      if (MODE == 0)
        srcp = (k0 < 128) ? (g.Ax + (long long)row * 128 + k0 + c * 8)
                          : (g.Aagg + (long long)row * 768 + (k0 - 128) + c * 8);
      else
        srcp = g.Ax + (long long)row * 128 + k0 + c * 8;
      uint4 u = *(const uint4*)srcp;
      ((uint4*)Ah)[r * 8 + (c ^ (r & 7))] = u;
    }
    // ---- stage B: 128 n-rows x 8 col16 units ----
#pragma unroll
    for (int p = 0; p < 4; ++p) {
      int idx = tid + 256 * p;
      int rn = idx >> 3, c = idx & 7;
      uint4 u = *(const uint4*)(Bt + (long long)rn * K + k0 + c * 8);
      ((uint4*)Bh)[rn * 8 + (c ^ (rn & 7))] = u;
    }
    __syncthreads();
    // ---- fragments + MFMA (2 K32 sub-steps) ----
#pragma unroll
    for (int ks = 0; ks < 2; ++ks) {
      half8 a[2], b[4];
#pragma unroll
      for (int fm = 0; fm < 2; ++fm) {
        int row = wm * 32 + fm * 16 + lr;
        a[fm] = *(const half8*)&((uint4*)Ah)[row * 8 + ((ks * 4 + lk) ^ (row & 7))];
      }
#pragma unroll
      for (int fn = 0; fn < 4; ++fn) {
        int col = wn * 64 + fn * 16 + lr;
        b[fn] = *(const half8*)&((uint4*)Bh)[col * 8 + ((ks * 4 + lk) ^ (col & 7))];
      }
#pragma unroll
      for (int fm = 0; fm < 2; ++fm)
#pragma unroll
        for (int fn = 0; fn < 4; ++fn)
          acc[fm][fn] = __builtin_amdgcn_mfma_f32_16x16x32_f16(a[fm], b[fn], acc[fm][fn], 0, 0, 0);
    }
  }

  // ---- epilogue ----
  const float CF = 0.08838834764831845f * 1.4426950408889634f;  // 1/sqrt(128)*log2(e)
  const float* bias = (MODE == 0) ? g.bias[0] : g.bias[z];
#pragma unroll
  for (int fm = 0; fm < 2; ++fm) {
#pragma unroll
    for (int fn = 0; fn < 4; ++fn) {
      int col = wn * 64 + fn * 16 + lr;
      float bv = bias[col];
#pragma unroll
      for (int j = 0; j < 4; ++j) {
        int row = m0 + wm * 32 + fm * 16 + lk * 4 + j;
        if (row < M) {
          float vv = acc[fm][fn][j] + bv;
          long long off = (long long)row * 128 + col;
          if (MODE == 0) {
            g.h[off] = f2h(vv);
          } else {
            if (z == 0) g.qh[off] = f2h(vv * CF);       // scale folded into q
            else if (z == 1) g.kh[off] = f2h(vv);
            else if (z == 2) g.vh[off] = f2h(vv);
            else g.sk[off] = vv;
          }
        }
      }
    }
  }
}

// ---------------------------------------------------------------------------
// CSR construction
// ---------------------------------------------------------------------------
__global__ void hist_kernel(const int* __restrict__ dst, int* __restrict__ deg, int E) {
  int e = blockIdx.x * blockDim.x + threadIdx.x;
  if (e < E) atomicAdd(&deg[dst[e]], 1);
}

__launch_bounds__(1024)
__global__ void scan1(const int* __restrict__ deg, int* __restrict__ incl,
                      int* __restrict__ part, int n) {
  __shared__ int sh[1024];
  int tid = threadIdx.x;
  int i = blockIdx.x * 1024 + tid;
  sh[tid] = (i < n) ? deg[i] : 0;
  __syncthreads();
  for (int o = 1; o < 1024; o <<= 1) {
    int t = (tid >= o) ? sh[tid - o] : 0;
    __syncthreads();
    sh[tid] += t;
    __syncthreads();
  }
  if (i < n) incl[i] = sh[tid];
  if (tid == 1023) part[blockIdx.x] = sh[1023];
}

// single-wave exclusive scan of block partials (was serial: ~600cy/elem chain)
__global__ void scan2(int* part, int nb) {
  int lane = threadIdx.x;  // 64 threads
  int run = 0;
  for (int b0 = 0; b0 < nb; b0 += 64) {
    int i = b0 + lane;
    int orig = (i < nb) ? part[i] : 0;
    int v = orig;
#pragma unroll
    for (int o = 1; o < 64; o <<= 1) {
      int t = __shfl_up(v, o);
      if (lane >= o) v += t;
    }
    if (i < nb) part[i] = run + v - orig;  // exclusive
    run += __shfl(v, 63);
  }
}

__global__ void scan3(const int* __restrict__ incl, const int* __restrict__ part,
                      int* __restrict__ offs, int n) {
  int i = blockIdx.x * blockDim.x + threadIdx.x;
  if (i < n) {
    offs[i + 1] = incl[i] + part[i >> 10];
    if (i == 0) offs[0] = 0;
  }
}

__global__ void scatter_kernel(const int* __restrict__ src, const int* __restrict__ dst,
                               const int* __restrict__ etype, const int* __restrict__ offs,
                               int* __restrict__ cur, int* __restrict__ csrc,
                               int* __restrict__ ctyp, int E) {
  int e = blockIdx.x * blockDim.x + threadIdx.x;
  if (e < E) {
    int d = dst[e];
    int p = offs[d] + atomicAdd(&cur[d], 1);
    csrc[p] = src[e];
    ctyp[p] = etype[e];
  }
}

// ---------------------------------------------------------------------------
// RGCN aggregation (aggregate-first, fp16 in / fp16 out), one WAVE per node.
// 4-edge unrolled chunks -> 4 gathers in flight; scalar (readfirstlane) switch.
// ---------------------------------------------------------------------------
__launch_bounds__(256)
__global__ void rgcn_agg(const unsigned short* __restrict__ xh, const int* __restrict__ offs,
                         const int* __restrict__ csrc, const int* __restrict__ ctyp,
                         unsigned short* __restrict__ aggh, int N) {
  int node = blockIdx.x * 4 + (threadIdx.x >> 6);
  if (node >= N) return;
  int lane = threadIdx.x & 63;
  int start = offs[node], end = offs[node + 1];

  float a0x = 0.f, a0y = 0.f, a1x = 0.f, a1y = 0.f, a2x = 0.f, a2y = 0.f;
  float a3x = 0.f, a3y = 0.f, a4x = 0.f, a4y = 0.f, a5x = 0.f, a5y = 0.f;
  int c0 = 0, c1 = 0, c2 = 0, c3 = 0, c4 = 0, c5 = 0;

#define ACC(T, XU)                                                         \
  {                                                                        \
    union { unsigned u; _Float16 h[2]; } cc; cc.u = (XU);                  \
    float fx = (float)cc.h[0], fy = (float)cc.h[1];                        \
    switch (T) {                                                           \
      case 0: a0x += fx; a0y += fy; ++c0; break;                           \
      case 1: a1x += fx; a1y += fy; ++c1; break;                           \
      case 2: a2x += fx; a2y += fy; ++c2; break;                           \
      case 3: a3x += fx; a3y += fy; ++c3; break;                           \
      case 4: a4x += fx; a4y += fy; ++c4; break;                           \
      default: a5x += fx; a5y += fy; ++c5; break;                          \
    }                                                                      \
  }

  int e = start;
  for (; e + 4 <= end; e += 4) {
    int s0 = csrc[e], s1 = csrc[e + 1], s2 = csrc[e + 2], s3 = csrc[e + 3];
    int t0 = __builtin_amdgcn_readfirstlane(ctyp[e]);
    int t1 = __builtin_amdgcn_readfirstlane(ctyp[e + 1]);
    int t2 = __builtin_amdgcn_readfirstlane(ctyp[e + 2]);
    int t3 = __builtin_amdgcn_readfirstlane(ctyp[e + 3]);
    unsigned x0 = ((const unsigned*)(xh + (long long)s0 * FDIM))[lane];
    unsigned x1 = ((const unsigned*)(xh + (long long)s1 * FDIM))[lane];
    unsigned x2 = ((const unsigned*)(xh + (long long)s2 * FDIM))[lane];
    unsigned x3 = ((const unsigned*)(xh + (long long)s3 * FDIM))[lane];
    ACC(t0, x0) ACC(t1, x1) ACC(t2, x2) ACC(t3, x3)
  }
  for (; e < end; ++e) {
    int s0 = csrc[e];
    int t0 = __builtin_amdgcn_readfirstlane(ctyp[e]);
    unsigned x0 = ((const unsigned*)(xh + (long long)s0 * FDIM))[lane];
    ACC(t0, x0)
  }
#undef ACC

  float i0 = c0 ? 1.f / (float)c0 : 0.f;
  float i1 = c1 ? 1.f / (float)c1 : 0.f;
  float i2 = c2 ? 1.f / (float)c2 : 0.f;
  float i3 = c3 ? 1.f / (float)c3 : 0.f;
  float i4 = c4 ? 1.f / (float)c4 : 0.f;
  float i5 = c5 ? 1.f / (float)c5 : 0.f;
  unsigned* ap = (unsigned*)(aggh + (long long)node * (NREL * FDIM));
  union { _Float16 h[2]; unsigned u; } p;
#define WR(ri, AX, AY, IV) { p.h[0] = (_Float16)((AX) * (IV)); p.h[1] = (_Float16)((AY) * (IV)); ap[(ri) * 64 + lane] = p.u; }
  WR(0, a0x, a0y, i0) WR(1, a1x, a1y, i1) WR(2, a2x, a2y, i2)
  WR(3, a3x, a3y, i3) WR(4, a4x, a4y, i4) WR(5, a5x, a5y, i5)
#undef WR
}

// ---------------------------------------------------------------------------
// TransformerConv edge-softmax, one WAVE per node, QUAD-edge processing:
// 16-lane group g dots edge e+g (8 feats/lane, uint4 fp16 k-load, fdot2).
// 4 xor-shuffles reduce in-group; 3 shuffles (16/32/48) broadcast all 4 scores.
// v loads in group-relative order s[g^j] -> weight/value pairing needs no
// selects (per-lane 4-edge sum is order-invariant). Log2-domain online
// softmax; scale pre-folded into q at the GEMM. 1-quad-ahead pipeline.
// ---------------------------------------------------------------------------
__launch_bounds__(256)
__global__ void attn_kernel(const unsigned short* __restrict__ qh,
                            const unsigned short* __restrict__ kh,
                            const unsigned short* __restrict__ vh,
                            const int* __restrict__ offs, const int* __restrict__ csrc,
                            float* __restrict__ out, int N) {
  int node = blockIdx.x * 4 + (threadIdx.x >> 6);
  if (node >= N) return;
  int lane = threadIdx.x & 63;
  int start = offs[node], end = offs[node + 1];
  int deg = end - start;
  if (deg <= 0) return;  // no incoming edges: attention adds 0

  const int g16 = lane >> 4;   // edge-group 0..3
  const int f = lane & 15;     // feat chunk (owns feats f*8..f*8+7 for the dot)

  union U4 { uint4 u; h16x2 h[4]; };
  U4 qf; qf.u = *(const uint4*)(qh + (long long)node * FDIM + f * 8);

  float m = -INFINITY, den = 0.f, acc0 = 0.f, acc1 = 0.f;

  // v-feature ownership for accumulation: lane owns feats (2*lane, 2*lane+1)
#define LOADQ(E0, S0, S1, S2, S3, KU, V0, V1, V2, V3)                        \
  {                                                                          \
    S0 = csrc[(E0) + (g16 ^ 0)];                                             \
    S1 = csrc[(E0) + (g16 ^ 1)];                                             \
    S2 = csrc[(E0) + (g16 ^ 2)];                                             \
    S3 = csrc[(E0) + (g16 ^ 3)];                                             \
    KU = *(const uint4*)(kh + (long long)S0 * FDIM + f * 8);                 \
    V0 = ((const unsigned*)(vh + (long long)S0 * FDIM))[lane];               \
    V1 = ((const unsigned*)(vh + (long long)S1 * FDIM))[lane];               \
    V2 = ((const unsigned*)(vh + (long long)S2 * FDIM))[lane];               \
    V3 = ((const unsigned*)(vh + (long long)S3 * FDIM))[lane];               \
  }

#define PROCESS(KU, V0, V1, V2, V3, MASKED, M0, M1, M2, M3)                  \
  {                                                                          \
    U4 kf; kf.u = KU;                                                        \
    float pd = FDOT2(qf.h[0], kf.h[0], 0.f);                                 \
    pd = FDOT2(qf.h[1], kf.h[1], pd);                                        \
    pd = FDOT2(qf.h[2], kf.h[2], pd);                                        \
    pd = FDOT2(qf.h[3], kf.h[3], pd);                                        \
    pd += __shfl_xor(pd, 1);  pd += __shfl_xor(pd, 2);                       \
    pd += __shfl_xor(pd, 4);  pd += __shfl_xor(pd, 8);                       \
    float sc0 = pd;                   /* edge e+(g^0) */                     \
    float sc1 = __shfl_xor(pd, 16);   /* edge e+(g^1) */                     \
    float sc2 = __shfl_xor(pd, 32);   /* edge e+(g^2) */                     \
    float sc3 = __shfl_xor(pd, 48);   /* edge e+(g^3) */                     \
    if (MASKED) {                                                            \
      if (!(M0)) sc0 = -INFINITY;                                            \
      if (!(M1)) sc1 = -INFINITY;                                            \
      if (!(M2)) sc2 = -INFINITY;                                            \
      if (!(M3)) sc3 = -INFINITY;                                            \
    }                                                                        \
    float mx = fmaxf(fmaxf(sc0, sc1), fmaxf(sc2, sc3));                      \
    float mn = fmaxf(m, mx);                                                 \
    float scl = exp2f(m - mn);                                               \
    float a0 = exp2f(sc0 - mn), a1 = exp2f(sc1 - mn);                        \
    float a2 = exp2f(sc2 - mn), a3 = exp2f(sc3 - mn);                        \
    den = den * scl + ((a0 + a1) + (a2 + a3));                               \
    union { unsigned u; _Float16 h[2]; } w0, w1, w2, w3;                     \
    w0.u = V0; w1.u = V1; w2.u = V2; w3.u = V3;                              \
    acc0 = acc0 * scl + a0 * (float)w0.h[0] + a1 * (float)w1.h[0]            \
                      + a2 * (float)w2.h[0] + a3 * (float)w3.h[0];           \
    acc1 = acc1 * scl + a0 * (float)w0.h[1] + a1 * (float)w1.h[1]            \
                      + a2 * (float)w2.h[1] + a3 * (float)w3.h[1];           \
    m = mn;                                                                  \
  }

  int nfull4 = deg & ~3;
  int e = start;
  if (nfull4 > 0) {
    int sA0, sA1, sA2, sA3; uint4 kA; unsigned vA0, vA1, vA2, vA3;
    LOADQ(e, sA0, sA1, sA2, sA3, kA, vA0, vA1, vA2, vA3)
    for (; e < start + nfull4; e += 4) {
      int sB0, sB1, sB2, sB3; uint4 kB; unsigned vB0, vB1, vB2, vB3;
      bool more = (e + 4 < start + nfull4);
      if (more) LOADQ(e + 4, sB0, sB1, sB2, sB3, kB, vB0, vB1, vB2, vB3)
      PROCESS(kA, vA0, vA1, vA2, vA3, false, 1, 1, 1, 1)
      if (more) { kA = kB; vA0 = vB0; vA1 = vB1; vA2 = vB2; vA3 = vB3; }
    }
  }
  int rem = deg & 3;
  if (rem) {
    int e0 = start + nfull4;
    int j0 = g16 ^ 0, j1 = g16 ^ 1, j2 = g16 ^ 2, j3 = g16 ^ 3;
    int sT0 = csrc[e0 + (j0 < rem ? j0 : 0)];
    int sT1 = csrc[e0 + (j1 < rem ? j1 : 0)];
    int sT2 = csrc[e0 + (j2 < rem ? j2 : 0)];
    int sT3 = csrc[e0 + (j3 < rem ? j3 : 0)];
    uint4 kT = *(const uint4*)(kh + (long long)sT0 * FDIM + f * 8);
    unsigned vT0 = ((const unsigned*)(vh + (long long)sT0 * FDIM))[lane];
    unsigned vT1 = ((const unsigned*)(vh + (long long)sT1 * FDIM))[lane];
    unsigned vT2 = ((const unsigned*)(vh + (long long)sT2 * FDIM))[lane];
    unsigned vT3 = ((const unsigned*)(vh + (long long)sT3 * FDIM))[lane];
    PROCESS(kT, vT0, vT1, vT2, vT3, true, j0 < rem, j1 < rem, j2 < rem, j3 < rem)
  }
#undef LOADQ
#undef PROCESS

  float inv = 1.f / den;
  float2* op = (float2*)(out + (long long)node * FDIM);
  float2 o = op[lane];
  o.x += acc0 * inv;
  o.y += acc1 * inv;
  op[lane] = o;
}

// ---------------------------------------------------------------------------
// BatchNorm (training stats) + LeakyReLU
// ---------------------------------------------------------------------------
__launch_bounds__(128)
__global__ void bn_stats(const float* __restrict__ x, float* __restrict__ gsum,
                         float* __restrict__ gsq, int N) {
  int d = threadIdx.x;
  float s = 0.f, qq = 0.f;
  for (int r = blockIdx.x; r < N; r += gridDim.x) {
    float vv = x[(long long)r * FDIM + d];
    s += vv;
    qq += vv * vv;
  }
  atomicAdd(&gsum[d], s);
  atomicAdd(&gsq[d], qq);
}

__global__ void bn_final(const float* __restrict__ gsum, const float* __restrict__ gsq,
                         const float* __restrict__ gamma, const float* __restrict__ beta,
                         float* __restrict__ ss, int N) {
  int d = threadIdx.x;
  if (d < FDIM) {
    float mean = gsum[d] / (float)N;
    float var = gsq[d] / (float)N - mean * mean;
    var = fmaxf(var, 0.f);
    float sc = gamma[d] * rsqrtf(var + 1e-5f);
    ss[d] = sc;
    ss[FDIM + d] = beta[d] - mean * sc;
  }
}

__global__ void bn_apply(float* __restrict__ x, const float* __restrict__ ss, long long total4) {
  long long i = (long long)blockIdx.x * blockDim.x + threadIdx.x;
  if (i < total4) {
    int d0 = (int)((i * 4) & (FDIM - 1));
    float4 vv = ((const float4*)x)[i];
    float y0 = ss[d0 + 0] * vv.x + ss[FDIM + d0 + 0];
    float y1 = ss[d0 + 1] * vv.y + ss[FDIM + d0 + 1];
    float y2 = ss[d0 + 2] * vv.z + ss[FDIM + d0 + 2];
    float y3 = ss[d0 + 3] * vv.w + ss[FDIM + d0 + 3];
    vv.x = (y0 > 0.f) ? y0 : 0.01f * y0;
    vv.y = (y1 > 0.f) ? y1 : 0.01f * y1;
    vv.z = (y2 > 0.f) ? y2 : 0.01f * y2;
    vv.w = (y3 > 0.f) ? y3 : 0.01f * y3;
    ((float4*)x)[i] = vv;
  }
}

// ---------------------------------------------------------------------------
// Launcher
// ---------------------------------------------------------------------------
extern "C" void kernel_launch(void* const* d_in, const int* in_sizes, int n_in,
                              void* d_out, int out_size, void* d_ws, size_t ws_size,
                              hipStream_t stream) {
  const float* x         = (const float*)d_in[0];
  const int*   ei        = (const int*)d_in[1];
  const int*   etype     = (const int*)d_in[2];
  const float* rgcn_w    = (const float*)d_in[3];
  const float* rgcn_root = (const float*)d_in[4];
  const float* rgcn_bias = (const float*)d_in[5];
  const float* wq = (const float*)d_in[6];  const float* bq = (const float*)d_in[7];
  const float* wk = (const float*)d_in[8];  const float* bk = (const float*)d_in[9];
  const float* wv = (const float*)d_in[10]; const float* bv = (const float*)d_in[11];
  const float* wsk = (const float*)d_in[12]; const float* bsk = (const float*)d_in[13];
  const float* gamma = (const float*)d_in[14]; const float* beta = (const float*)d_in[15];

  const int N = in_sizes[0] / FDIM;
  const int E = in_sizes[1] / 2;
  const int* src = ei;
  const int* dst = ei + E;

  // ---- workspace layout (byte-offset, 256B-aligned chunks) ----
  char* base = (char*)d_ws;
  size_t off = 0;
  auto alloc = [&](size_t bytes) -> char* {
    char* p = base + off;
    off += (bytes + 255) & ~(size_t)255;
    return p;
  };
  unsigned short* aggh = (unsigned short*)alloc((size_t)N * (NREL * FDIM) * 2);  // 76.8MB
  // q/k/v (all fp16) reuse the agg region after the RGCN GEMM consumes it:
  unsigned short* qbuf = aggh;                                // N*128 fp16
  unsigned short* kbuf = aggh + (size_t)N * FDIM;             // N*128 fp16
  unsigned short* vbuf = aggh + 2 * (size_t)N * FDIM;         // N*128 fp16
  unsigned short* xh   = (unsigned short*)alloc((size_t)N * FDIM * 2);
  unsigned short* hh   = (unsigned short*)alloc((size_t)N * FDIM * 2);
  unsigned short* btR  = (unsigned short*)alloc((size_t)896 * 128 * 2);
  unsigned short* btQ  = (unsigned short*)alloc((size_t)4 * 128 * 128 * 2);
  int* deg  = (int*)alloc((size_t)2 * N * 4);           // deg + cur (contiguous)
  int* cur  = deg + N;
  int* offs = (int*)alloc((size_t)(N + 1) * 4);
  int* incl = (int*)alloc((size_t)N * 4);
  int* part = (int*)alloc((size_t)64 * 4);
  int* csrc = (int*)alloc((size_t)E * 4);
  int* ctyp = (int*)alloc((size_t)E * 4);
  float* gsum = (float*)alloc((size_t)(128 + 128 + 256) * 4);
  float* gsq  = gsum + FDIM;
  float* ss   = gsum + 2 * FDIM;

  float* out = (float*)d_out;

  hipMemsetAsync(deg, 0, (size_t)2 * N * sizeof(int), stream);        // deg + cur
  hipMemsetAsync(gsum, 0, (size_t)2 * FDIM * sizeof(float), stream);  // gsum + gsq

  // ---- conversions ----
  int n4 = N * FDIM / 4;
  cvt_x_kernel<<<(n4 + 255) / 256, 256, 0, stream>>>(x, xh, n4);
  cvt_wr_kernel<<<(896 * 128 + 255) / 256, 256, 0, stream>>>(rgcn_root, rgcn_w, btR);
  WPtrs wp; wp.W[0] = wq; wp.W[1] = wk; wp.W[2] = wv; wp.W[3] = wsk;
  cvt_wq_kernel<<<(4 * 128 * 128 + 255) / 256, 256, 0, stream>>>(wp, btQ);

  // ---- CSR build (by dst) ----
  hist_kernel<<<(E + 255) / 256, 256, 0, stream>>>(dst, deg, E);
  int nb = (N + 1023) / 1024;
  scan1<<<nb, 1024, 0, stream>>>(deg, incl, part, N);
  scan2<<<1, 64, 0, stream>>>(part, nb);
  scan3<<<(N + 255) / 256, 256, 0, stream>>>(incl, part, offs, N);
  scatter_kernel<<<(E + 255) / 256, 256, 0, stream>>>(src, dst, etype, offs, cur, csrc, ctyp, E);

  const int nodeBlocks = (N + 3) / 4;
  const int gemmBlocks = (N + 63) / 64;

  // ---- RGCN: aggregate-first (fp16), then fused K=896 MFMA GEMM -> h (fp16) ----
  rgcn_agg<<<nodeBlocks, 256, 0, stream>>>(xh, offs, csrc, ctyp, aggh, N);

  GArgs g0 = {};
  g0.Ax = xh; g0.Aagg = aggh; g0.Bt = btR;
  g0.bias[0] = rgcn_bias;
  g0.h = hh; g0.M = N; g0.K = 896;
  gemm_mfma<0><<<dim3(gemmBlocks, 1, 1), 256, 0, stream>>>(g0);

  // ---- q,k,v,skip projections (z=4): q/k/v fp16 (q pre-scaled), skip f32 -> out ----
  GArgs g1 = {};
  g1.Ax = hh; g1.Bt = btQ;
  g1.bias[0] = bq; g1.bias[1] = bk; g1.bias[2] = bv; g1.bias[3] = bsk;
  g1.qh = qbuf; g1.kh = kbuf; g1.vh = vbuf; g1.sk = out;
  g1.M = N; g1.K = 128;
  gemm_mfma<1><<<dim3(gemmBlocks, 1, 4), 256, 0, stream>>>(g1);

  // ---- edge-softmax attention (accumulates into out) ----
  attn_kernel<<<nodeBlocks, 256, 0, stream>>>(qbuf, kbuf, vbuf, offs, csrc, out, N);

  // ---- BatchNorm (training stats) + LeakyReLU, in place on out ----
  bn_stats<<<512, 128, 0, stream>>>(out, gsum, gsq, N);
  bn_final<<<1, 128, 0, stream>>>(gsum, gsq, gamma, beta, ss, N);
  long long total4 = (long long)N * FDIM / 4;
  bn_apply<<<(int)((total4 + 255) / 256), 256, 0, stream>>>(out, ss, total4);
}